// Round 13
// baseline (338.942 us; speedup 1.0000x reference)
//
#include <hip/hip_runtime.h>

typedef short bf16x8 __attribute__((ext_vector_type(8)));
typedef float f32x4  __attribute__((ext_vector_type(4)));

__device__ __forceinline__ unsigned short f2b(float f){
  union { float f; unsigned u; } v; v.f = f;
  unsigned r = v.u + 0x7FFFu + ((v.u >> 16) & 1u);
  return (unsigned short)(r >> 16);
}
__device__ __forceinline__ float b2f(unsigned short s){
  union { unsigned u; float f; } v; v.u = ((unsigned)s) << 16;
  return v.f;
}
__device__ __forceinline__ unsigned pk2(float lo, float hi){
  unsigned r;
  asm("v_cvt_pk_bf16_f32 %0, %1, %2" : "=v"(r) : "v"(lo), "v"(hi));
  return r;
}

// ---------------- stage 1: qkv GEMM (192 blocks) + RNN (16 blocks, independent) ----------------
__global__ void k_pre1(const float* __restrict__ FE, const float* __restrict__ W_in,
                       float* __restrict__ Qm, float* __restrict__ Km, float* __restrict__ Vm,
                       const float* __restrict__ x_cont, const float* __restrict__ z0,
                       const float* __restrict__ W_ih, const float* __restrict__ W_hh,
                       const float* __restrict__ b_ih, const float* __restrict__ b_hh,
                       const float* __restrict__ Uf, const float* __restrict__ Wfp,
                       const float* __restrict__ bfp, float* __restrict__ zout){
  int bid = blockIdx.x;
  int tid = threadIdx.x;
  if (bid < 192){
    int id = bid*256 + tid;
    int part = id >> 14;
    int l = (id >> 8) & 63;
    int d = id & 255;
    const float4* fe = (const float4*)(FE + l*256);
    const float4* wr = (const float4*)(W_in + (part*256 + d)*256);
    float s = 0.f;
    #pragma unroll 8
    for (int k=0;k<64;k++){
      float4 a = fe[k], b = wr[k];
      s += a.x*b.x + a.y*b.y + a.z*b.z + a.w*b.w;
    }
    float* dst = (part==0)?Qm:((part==1)?Km:Vm);
    dst[l*256+d] = s;
    return;
  }
  {
    // ---- RNN: blocks 192..207, lanes 0..63 active ----
    int b = bid - 192;
    int l = tid;
    bool act = (l < 64);
    __shared__ float h_sh[64];
    __shared__ float fh_sh[24];
    __shared__ float WfpT[24][64];
    float wr[64];
    float wih=0, bb=0, bf=0;
    float uf0=0,uf1=0,uf2=0,uf3=0;
    if (act){
      #pragma unroll
      for (int j=0;j<64;j++) wr[j] = W_hh[l*64+j];
      #pragma unroll
      for (int j=0;j<24;j++) WfpT[j][l] = Wfp[l*24+j];
      wih = W_ih[l];
      bb  = b_ih[l] + b_hh[l];
      bf  = bfp[l];
      if (l < 24){ uf0=Uf[l*4+0]; uf1=Uf[l*4+1]; uf2=Uf[l*4+2]; uf3=Uf[l*4+3]; }
      h_sh[l] = z0[l];
    }
    __syncthreads();
    const float* xb = x_cont + (size_t)b*128*97;
    for (int t=0;t<128;t++){
      float hn = 0.f, fh = 0.f;
      if (act){
        float x0 = xb[t*97];
        float a0=0,a1=0,a2=0,a3=0;
        #pragma unroll
        for (int j=0;j<64;j+=4){
          a0 += wr[j  ]*h_sh[j  ];
          a1 += wr[j+1]*h_sh[j+1];
          a2 += wr[j+2]*h_sh[j+2];
          a3 += wr[j+3]*h_sh[j+3];
        }
        hn = fmaxf(x0*wih + bb + ((a0+a1)+(a2+a3)), 0.f);
        if (l < 24){
          const float* xf = xb + t*97 + 1 + l*4;
          fh = xf[0]*uf0 + xf[1]*uf1 + xf[2]*uf2 + xf[3]*uf3;
        }
      }
      __syncthreads();
      if (act){
        h_sh[l] = hn;
        if (l < 24) fh_sh[l] = fh;
      }
      __syncthreads();
      if (act){
        float zv = hn + bf;
        #pragma unroll
        for (int j=0;j<24;j++) zv += fh_sh[j]*WfpT[j][l];
        zout[((size_t)b*128 + t)*64 + l] = zv;
      }
    }
  }
}

// ---------------- stage 2: fragment-coalesced tables (exp2-scaled attention tables) ----------------
__global__ void k_pre2(const float* __restrict__ Qm, const float* __restrict__ Km,
                       const float* __restrict__ Vm,
                       const float* __restrict__ b_in, const float* __restrict__ W_ao,
                       const float* __restrict__ b_ao, const float* __restrict__ FE,
                       float* __restrict__ Gc, float* __restrict__ U,
                       float* __restrict__ W, float* __restrict__ S,
                       float* __restrict__ abias, short* __restrict__ M2c,
                       const float* __restrict__ W1, const float* __restrict__ W2,
                       short* __restrict__ W1c, short* __restrict__ W2c,
                       float* __restrict__ FEc){
  int bid = blockIdx.x;
  int tid = threadIdx.x;
  // attention tables pre-scaled by log2(e): softmax runs in exp2 domain
  const float inv = 0.17677669529663687f * 1.4426950408889634f;
  if (bid < 198){
    int id = bid*256 + tid;
    if (id < 32768){
      int h = id >> 12, ks = (id>>11)&1, w4 = (id>>9)&3, lane = (id>>3)&63, j = id&7;
      int lq = w4*16 + (lane&15);
      int lk = ks*32 + (lane>>4)*8 + j;
      const float* qp = Qm + lq*256 + h*32;
      const float* kp = Km + lk*256 + h*32;
      float s=0.f;
      #pragma unroll
      for (int d=0;d<32;d++) s += qp[d]*kp[d];
      Gc[id] = s*inv;
    } else if (id < 33280){
      int j = id - 32768; int h = j>>6, lq = j&63;
      const float* qp = Qm + lq*256 + h*32;
      const float* bk = b_in + 256 + h*32;
      float s=0.f;
      #pragma unroll
      for (int d=0;d<32;d++) s += qp[d]*bk[d];
      U[j] = s*inv;
    } else if (id < 33792){
      int j = id - 33280; int h = j>>6, lk = j&63;
      const float* kp = Km + lk*256 + h*32;
      const float* bq = b_in + h*32;
      float s=0.f;
      #pragma unroll
      for (int d=0;d<32;d++) s += bq[d]*kp[d];
      W[j] = s*inv;
    } else if (id < 33800){
      int h = id - 33792;
      float s=0.f;
      #pragma unroll
      for (int d=0;d<32;d++) s += b_in[h*32+d]*b_in[256+h*32+d];
      S[h] = s*inv;
    } else if (id < 34056){
      int e = id - 33800;
      float s = b_ao[e];
      for (int d=0; d<256; d++) s += b_in[512+d]*W_ao[e*256+d];
      abias[e] = s;
    } else if (id < 50440){
      int o = id - 34056;
      int tt = o>>12, et = (o>>10)&3, w4 = (o>>8)&3, lane = (o>>2)&63, j = o&3;
      int row = tt*16 + (lane&15);
      int col = w4*64 + et*16 + (lane>>4)*4 + j;
      FEc[o] = FE[row*256 + col];
    }
    return;
  }
  if (bid < 710){
    int o = (bid-198)*256 + tid;
    int h = o>>14, ks = (o>>13)&1, w4 = (o>>11)&3, et = (o>>9)&3, lane = (o>>3)&63, j = o&7;
    int e = w4*64 + et*16 + (lane&15);
    int lk = ks*32 + (lane>>4)*8 + j;
    const float* vp = Vm + lk*256 + h*32;
    const float* wp = W_ao + e*256 + h*32;
    float s=0.f;
    #pragma unroll
    for (int d=0;d<32;d++) s += vp[d]*wp[d];
    M2c[o] = (short)f2b(s);
    return;
  }
  {
    // W1c/W2c: coalesced linear read, scattered write
    int id3 = (bid-710)*256 + tid;
    if (id3 < 262144){
      int row = id3 >> 8, col = id3 & 255;       // W1[1024][256]
      int c = row >> 7, w4 = (row>>5)&3, ct = (row>>4)&1, lrow = row & 15;
      int ks = col >> 5, lhi = (col>>3)&3, j = col & 7;
      int o = c*32768 + ks*4096 + w4*1024 + ct*512 + (lhi*16+lrow)*8 + j;
      W1c[o] = (short)f2b(W1[id3]);
    } else {
      int idx = id3 - 262144;
      int row = idx >> 10, col = idx & 1023;     // W2[256][1024]
      int w4 = row >> 6, et = (row>>4)&3, lrow = row & 15;
      int c = col >> 7, ks2 = (col>>5)&3, lhi = (col>>3)&3, j = col & 7;
      int o = c*32768 + ks2*8192 + w4*2048 + et*512 + (lhi*16+lrow)*8 + j;
      W2c[o] = (short)f2b(W2[idx]);
    }
    return;
  }
}

// ---------------- fused per-token transformer block (2048 blocks x 256 thr) ----------------
// 3 blocks/CU; exp2-domain softmax with hoisted zq*zk products (2 FMA/logit).
__global__ __launch_bounds__(256, 3) void k_main(
  const float* __restrict__ zall, const float* __restrict__ Gc,
  const float* __restrict__ Ubuf, const float* __restrict__ Wbuf, const float* __restrict__ Sbuf,
  const float* __restrict__ abias, const short* __restrict__ M2c,
  const float* __restrict__ FEc,
  const short* __restrict__ W1c, const float* __restrict__ b1,
  const short* __restrict__ W2c, const float* __restrict__ b2,
  const float* __restrict__ g1, const float* __restrict__ be1,
  const float* __restrict__ g2, const float* __restrict__ be2,
  const float* __restrict__ Wop, const float* __restrict__ bop,
  const float* __restrict__ Wg, const float* __restrict__ bg,
  const float* __restrict__ Amat, const float* __restrict__ cvec,
  float* __restrict__ out)
{
  const int n = blockIdx.x;
  const int tid = threadIdx.x;
  const int w = tid >> 6, lane = tid & 63, lg = lane >> 4, lr = lane & 15;
  const int cb = w * 64;

  __shared__ __align__(16) short t1_sh[64][264];   // 33792 B
  __shared__ __align__(16) char  upool[17408];     // union: mid[64][136] | pa[2][4][2][64][8]
  __shared__ float redA[4][64];
  __shared__ float redB[4][64];
  __shared__ float z_sh[64];                       // 53504 B -> 3 blocks/CU

  short (*mid_sh)[136] = reinterpret_cast<short (*)[136]>(upool);
  short (*pa_sh)[4][2][64][8] = reinterpret_cast<short (*)[4][2][64][8]>(upool);

  if (tid < 64) z_sh[tid] = zall[n*64 + tid];
  __syncthreads();   // Z0

  float zkf[16];
  #pragma unroll
  for (int i=0;i<16;i++) zkf[i] = z_sh[(i>>3)*32 + lg*8 + (i&7)];

  // shared accumulator: attention acc, later reused as FFN outv (64 AGPR total)
  f32x4 acc[4][4];
  #pragma unroll
  for (int et=0;et<4;et++)
    #pragma unroll
    for (int tt=0;tt<4;tt++){ f32x4 zz = {0.f,0.f,0.f,0.f}; acc[et][tt] = zz; }

  const int lq_own = w*16 + lr;
  const float zq_own = z_sh[lq_own];
  float zqzk[16];
  #pragma unroll
  for (int i=0;i<16;i++) zqzk[i] = zq_own * zkf[i];

  #pragma unroll 1
  for (int h=0; h<8; ++h){
    // --- softmax (exp2 domain) for rows of quarter tt==w ---
    {
      const float base = zq_own * Ubuf[h*64 + lq_own] + Sbuf[h];
      float e0[16];
      #pragma unroll
      for (int ks=0;ks<2;ks++){
        const float* gbase = Gc + h*4096 + ks*2048 + w*512 + lane*8;
        f32x4 ga = *(const f32x4*)(gbase);
        f32x4 gb = *(const f32x4*)(gbase + 4);
        f32x4 wa = *(const f32x4*)(Wbuf + h*64 + ks*32 + lg*8);
        f32x4 wb = *(const f32x4*)(Wbuf + h*64 + ks*32 + lg*8 + 4);
        #pragma unroll
        for (int j=0;j<4;j++){
          e0[ks*8+j]   = fmaf(zqzk[ks*8+j],   ga[j], fmaf(zkf[ks*8+j],   wa[j], base));
          e0[ks*8+4+j] = fmaf(zqzk[ks*8+4+j], gb[j], fmaf(zkf[ks*8+4+j], wb[j], base));
        }
      }
      float mx = e0[0];
      #pragma unroll
      for (int i=1;i<16;i++) mx = fmaxf(mx, e0[i]);
      mx = fmaxf(mx, __shfl_xor(mx,16));
      mx = fmaxf(mx, __shfl_xor(mx,32));
      float sum = 0.f;
      #pragma unroll
      for (int i=0;i<16;i++){ e0[i] = exp2f(e0[i]-mx); sum += e0[i]; }
      sum += __shfl_xor(sum,16);
      sum += __shfl_xor(sum,32);
      float inv = __builtin_amdgcn_rcpf(sum);
      #pragma unroll
      for (int ks=0;ks<2;ks++){
        union { bf16x8 v; unsigned u[4]; } pa;
        #pragma unroll
        for (int p=0;p<4;p++)
          pa.u[p] = pk2(e0[ks*8+2*p]*inv*zkf[ks*8+2*p], e0[ks*8+2*p+1]*inv*zkf[ks*8+2*p+1]);
        *(bf16x8*)&pa_sh[h&1][w][ks][lane][0] = pa.v;
      }
    }
    __syncthreads();   // pa[h&1] ready
    __builtin_amdgcn_s_setprio(1);
    #pragma unroll
    for (int ks=0; ks<2; ks++){
      bf16x8 am[4], bt[4];
      #pragma unroll
      for (int et=0;et<4;et++)
        am[et] = *(const bf16x8*)(M2c + h*16384 + ks*8192 + w*2048 + et*512 + lane*8);
      #pragma unroll
      for (int tt=0;tt<4;tt++) bt[tt] = *(const bf16x8*)&pa_sh[h&1][tt][ks][lane][0];
      #pragma unroll
      for (int et=0;et<4;et++)
        #pragma unroll
        for (int tt=0;tt<4;tt++)
          acc[et][tt] = __builtin_amdgcn_mfma_f32_16x16x32_bf16(am[et], bt[tt], acc[et][tt], 0,0,0);
    }
    __builtin_amdgcn_s_setprio(0);
  }

  // ---------- t1 = LN(tokens + aop) ----------
  f32x4 ab4[4], g14[4], be14[4];
  #pragma unroll
  for (int et=0;et<4;et++){
    int e0_ = cb + et*16 + lg*4;
    ab4[et]  = *(const f32x4*)(abias + e0_);
    g14[et]  = *(const f32x4*)(g1 + e0_);
    be14[et] = *(const f32x4*)(be1 + e0_);
  }
  float sum1[4], ssq1[4];
  #pragma unroll
  for (int tt=0;tt<4;tt++){
    int tok = tt*16 + lr;
    float zt = z_sh[tok];
    float s = 0.f, sq = 0.f;
    #pragma unroll
    for (int et=0;et<4;et++){
      f32x4 fe = *(const f32x4*)(FEc + tt*4096 + et*1024 + w*256 + lane*4);
      #pragma unroll
      for (int r=0;r<4;r++){
        float v = acc[et][tt][r] + ab4[et][r] + zt*fe[r];
        acc[et][tt][r] = v; s += v; sq += v*v;
      }
    }
    s  += __shfl_xor(s,16);  s  += __shfl_xor(s,32);
    sq += __shfl_xor(sq,16); sq += __shfl_xor(sq,32);
    sum1[tt] = s; ssq1[tt] = sq;
  }
  if (lane < 16){
    #pragma unroll
    for (int tt=0;tt<4;tt++){ redA[w][tt*16+lane] = sum1[tt]; redB[w][tt*16+lane] = ssq1[tt]; }
  }
  __syncthreads();   // S1
  float mu1[4], rs1[4];
  #pragma unroll
  for (int tt=0;tt<4;tt++){
    int tok = tt*16 + lr;
    float s  = redA[0][tok] + redA[1][tok] + redA[2][tok] + redA[3][tok];
    float sq = redB[0][tok] + redB[1][tok] + redB[2][tok] + redB[3][tok];
    float m = s * (1.f/256.f);
    mu1[tt] = m;
    rs1[tt] = rsqrtf(sq*(1.f/256.f) - m*m + 1e-5f);
  }
  #pragma unroll
  for (int et=0;et<4;et++)
    #pragma unroll
    for (int tt=0;tt<4;tt++){
      uint2 p;
      float v0 = (acc[et][tt][0]-mu1[tt])*rs1[tt]*g14[et][0] + be14[et][0];
      float v1 = (acc[et][tt][1]-mu1[tt])*rs1[tt]*g14[et][1] + be14[et][1];
      float v2 = (acc[et][tt][2]-mu1[tt])*rs1[tt]*g14[et][2] + be14[et][2];
      float v3 = (acc[et][tt][3]-mu1[tt])*rs1[tt]*g14[et][3] + be14[et][3];
      p.x = pk2(v0,v1); p.y = pk2(v2,v3);
      *(uint2*)&t1_sh[tt*16+lr][cb + et*16 + lg*4] = p;
    }
  __syncthreads();   // T1 (last pa reads done -> upool reusable as mid)

  // ---------- FFN: 8 chunks, single mid, 2 barriers/chunk (acc reused as outv) ----------
  #pragma unroll
  for (int et=0;et<4;et++)
    #pragma unroll
    for (int tt=0;tt<4;tt++){ f32x4 zz = {0.f,0.f,0.f,0.f}; acc[et][tt] = zz; }

  #pragma unroll 1
  for (int c=0; c<8; c++){
    f32x4 midv[2][4];
    #pragma unroll
    for (int ct=0;ct<2;ct++){
      f32x4 bi = *(const f32x4*)(b1 + c*128 + w*32 + ct*16 + lg*4);
      #pragma unroll
      for (int tt=0;tt<4;tt++) midv[ct][tt] = bi;
    }
    #pragma unroll
    for (int ks=0; ks<8; ks++){
      bf16x8 bt[4], aw[2];
      #pragma unroll
      for (int tt=0;tt<4;tt++) bt[tt] = *(const bf16x8*)&t1_sh[tt*16+lr][ks*32 + lg*8];
      #pragma unroll
      for (int ct=0;ct<2;ct++)
        aw[ct] = *(const bf16x8*)(W1c + c*32768 + ks*4096 + w*1024 + ct*512 + lane*8);
      #pragma unroll
      for (int ct=0;ct<2;ct++)
        #pragma unroll
        for (int tt=0;tt<4;tt++)
          midv[ct][tt] = __builtin_amdgcn_mfma_f32_16x16x32_bf16(aw[ct], bt[tt], midv[ct][tt], 0,0,0);
    }
    __syncthreads();       // prior FFN2 reads of mid done
    #pragma unroll
    for (int ct=0;ct<2;ct++)
      #pragma unroll
      for (int tt=0;tt<4;tt++){
        uint2 p;
        p.x = pk2(fmaxf(midv[ct][tt][0],0.f), fmaxf(midv[ct][tt][1],0.f));
        p.y = pk2(fmaxf(midv[ct][tt][2],0.f), fmaxf(midv[ct][tt][3],0.f));
        *(uint2*)&mid_sh[tt*16+lr][w*32 + ct*16 + lg*4] = p;
      }
    __syncthreads();
    __builtin_amdgcn_s_setprio(1);
    #pragma unroll
    for (int ks2=0; ks2<4; ks2++){
      bf16x8 aw2[4], bm[4];
      #pragma unroll
      for (int et=0;et<4;et++)
        aw2[et] = *(const bf16x8*)(W2c + c*32768 + ks2*8192 + w*2048 + et*512 + lane*8);
      #pragma unroll
      for (int tt=0;tt<4;tt++) bm[tt] = *(const bf16x8*)&mid_sh[tt*16+lr][ks2*32 + lg*8];
      #pragma unroll
      for (int et=0;et<4;et++)
        #pragma unroll
        for (int tt=0;tt<4;tt++)
          acc[et][tt] = __builtin_amdgcn_mfma_f32_16x16x32_bf16(aw2[et], bm[tt], acc[et][tt], 0,0,0);
    }
    __builtin_amdgcn_s_setprio(0);
  }

  // ---------- t2 = LN(t1 + ffn), delta, z_out, o ----------
  f32x4 b24[4], g24[4], be24[4], wop4[4];
  #pragma unroll
  for (int et=0;et<4;et++){
    int e0_ = cb + et*16 + lg*4;
    b24[et]  = *(const f32x4*)(b2 + e0_);
    g24[et]  = *(const f32x4*)(g2 + e0_);
    be24[et] = *(const f32x4*)(be2 + e0_);
    wop4[et] = *(const f32x4*)(Wop + e0_);
  }
  float sum2[4], ssq2[4];
  #pragma unroll
  for (int tt=0;tt<4;tt++){
    int tok = tt*16 + lr;
    float s = 0.f, sq = 0.f;
    #pragma unroll
    for (int et=0;et<4;et++){
      uint2 t1v = *(const uint2*)&t1_sh[tok][cb + et*16 + lg*4];
      #pragma unroll
      for (int r=0;r<4;r++){
        unsigned short hs = (unsigned short)((r&1) ? ((r<2?t1v.x:t1v.y)>>16) : ((r<2?t1v.x:t1v.y)&0xFFFF));
        float v = acc[et][tt][r] + b24[et][r] + b2f(hs);
        acc[et][tt][r] = v; s += v; sq += v*v;
      }
    }
    s  += __shfl_xor(s,16);  s  += __shfl_xor(s,32);
    sq += __shfl_xor(sq,16); sq += __shfl_xor(sq,32);
    sum2[tt] = s; ssq2[tt] = sq;
  }
  if (lane < 16){
    #pragma unroll
    for (int tt=0;tt<4;tt++){ redA[w][tt*16+lane] = sum2[tt]; redB[w][tt*16+lane] = ssq2[tt]; }
  }
  __syncthreads();   // B2

  float gate = 0.f;
  if (tid < 64){
    float gacc = bg[tid];
    const f32x4* wgr = (const f32x4*)(Wg + tid*64);
    #pragma unroll
    for (int j=0;j<16;j++){
      f32x4 wv = wgr[j];
      f32x4 zv = *(const f32x4*)(z_sh + j*4);
      gacc += wv[0]*zv[0] + wv[1]*zv[1] + wv[2]*zv[2] + wv[3]*zv[3];
    }
    gate = 1.f/(1.f + __expf(-gacc));
  }

  float dpart[4];
  #pragma unroll
  for (int tt=0;tt<4;tt++){
    int tok = tt*16 + lr;
    float s  = redA[0][tok] + redA[1][tok] + redA[2][tok] + redA[3][tok];
    float sq = redB[0][tok] + redB[1][tok] + redB[2][tok] + redB[3][tok];
    float m = s * (1.f/256.f);
    float rs = rsqrtf(sq*(1.f/256.f) - m*m + 1e-5f);
    float d = 0.f;
    #pragma unroll
    for (int et=0;et<4;et++)
      #pragma unroll
      for (int r=0;r<4;r++){
        float t2 = (acc[et][tt][r]-m)*rs*g24[et][r] + be24[et][r];
        d += t2*wop4[et][r];
      }
    d += __shfl_xor(d,16); d += __shfl_xor(d,32);
    dpart[tt] = d;
  }
  __syncthreads();   // N1
  if (lane < 16){
    #pragma unroll
    for (int tt=0;tt<4;tt++) redA[w][tt*16+lane] = dpart[tt];
  }
  __syncthreads();   // D2
  if (tid < 64){
    float delta = redA[0][tid]+redA[1][tid]+redA[2][tid]+redA[3][tid] + bop[0];
    float zo = z_sh[tid] + gate*delta;
    out[49152 + (size_t)n*64 + tid] = zo;
    z_sh[tid] = zo;
  }
  __syncthreads();   // E2
  if (tid < 24){
    const float* ar = Amat + tid*64;
    float s = cvec[tid];
    #pragma unroll
    for (int j=0;j<64;j++) s += z_sh[j]*ar[j];
    out[(size_t)n*24 + tid] = s;
  }
}

extern "C" void kernel_launch(void* const* d_in, const int* in_sizes, int n_in,
                              void* d_out, int out_size, void* d_ws, size_t ws_size,
                              hipStream_t stream) {
  const float* x_cont = (const float*)d_in[0];
  const float* z0    = (const float*)d_in[1];
  const float* W_ih  = (const float*)d_in[2];
  const float* W_hh  = (const float*)d_in[3];
  const float* b_ih  = (const float*)d_in[4];
  const float* b_hh  = (const float*)d_in[5];
  const float* Uf    = (const float*)d_in[6];
  const float* Wfp   = (const float*)d_in[7];
  const float* bfp   = (const float*)d_in[8];
  const float* FE    = (const float*)d_in[9];
  const float* W_in  = (const float*)d_in[10];
  const float* b_in  = (const float*)d_in[11];
  const float* W_ao  = (const float*)d_in[12];
  const float* b_ao  = (const float*)d_in[13];
  const float* g1    = (const float*)d_in[14];
  const float* be1   = (const float*)d_in[15];
  const float* W1    = (const float*)d_in[16];
  const float* b1    = (const float*)d_in[17];
  const float* W2    = (const float*)d_in[18];
  const float* b2    = (const float*)d_in[19];
  const float* g2    = (const float*)d_in[20];
  const float* be2   = (const float*)d_in[21];
  const float* Wop   = (const float*)d_in[22];
  const float* bop   = (const float*)d_in[23];
  const float* Wg    = (const float*)d_in[24];
  const float* bg    = (const float*)d_in[25];
  const float* Amat  = (const float*)d_in[26];
  const float* cvec  = (const float*)d_in[27];
  float* out = (float*)d_out;
  char* ws = (char*)d_ws;

  float* z    = (float*)(ws + 0);         // 524288
  float* Qm   = (float*)(ws + 524288);    // 65536
  float* Km   = (float*)(ws + 589824);
  float* Vm   = (float*)(ws + 655360);
  float* Gc   = (float*)(ws + 720896);    // 131072
  float* U    = (float*)(ws + 851968);    // 2048
  float* Wb   = (float*)(ws + 854016);    // 2048
  float* S    = (float*)(ws + 856064);    // 256
  float* ab   = (float*)(ws + 856320);    // 1024
  short* M2c  = (short*)(ws + 857344);    // 262144
  short* W1c  = (short*)(ws + 1119488);   // 524288
  short* W2c  = (short*)(ws + 1643776);   // 524288
  float* FEc  = (float*)(ws + 2168064);   // 65536

  hipLaunchKernelGGL(k_pre1, dim3(208), dim3(256), 0, stream,
                     FE, W_in, Qm, Km, Vm,
                     x_cont, z0, W_ih, W_hh, b_ih, b_hh, Uf, Wfp, bfp, z);
  hipLaunchKernelGGL(k_pre2, dim3(2758), dim3(256), 0, stream,
                     Qm, Km, Vm, b_in, W_ao, b_ao, FE, Gc, U, Wb, S, ab, M2c,
                     W1, W2, W1c, W2c, FEc);
  hipLaunchKernelGGL(k_main, dim3(2048), dim3(256), 0, stream, z, Gc, U, Wb, S, ab, M2c, FEc,
                     W1c, b1, W2c, b2, g1, be1, g2, be2, Wop, bop, Wg, bg, Amat, cvec, out);
}

// Round 14
// 317.616 us; speedup vs baseline: 1.0671x; 1.0671x over previous
//
#include <hip/hip_runtime.h>

typedef short bf16x8 __attribute__((ext_vector_type(8)));
typedef float f32x4  __attribute__((ext_vector_type(4)));

__device__ __forceinline__ unsigned short f2b(float f){
  union { float f; unsigned u; } v; v.f = f;
  unsigned r = v.u + 0x7FFFu + ((v.u >> 16) & 1u);
  return (unsigned short)(r >> 16);
}
__device__ __forceinline__ float b2f(unsigned short s){
  union { unsigned u; float f; } v; v.u = ((unsigned)s) << 16;
  return v.f;
}
__device__ __forceinline__ unsigned pk2(float lo, float hi){
  unsigned r;
  asm("v_cvt_pk_bf16_f32 %0, %1, %2" : "=v"(r) : "v"(lo), "v"(hi));
  return r;
}

// ---------------- stage 1: qkv GEMM (192 blocks) ----------------
__global__ void k_pre_qkv(const float* __restrict__ FE, const float* __restrict__ W_in,
                          float* __restrict__ Qm, float* __restrict__ Km, float* __restrict__ Vm){
  int id = blockIdx.x*256 + threadIdx.x;
  int part = id >> 14;
  int l = (id >> 8) & 63;
  int d = id & 255;
  const float4* fe = (const float4*)(FE + l*256);
  const float4* wr = (const float4*)(W_in + (part*256 + d)*256);
  float s = 0.f;
  #pragma unroll 8
  for (int k=0;k<64;k++){
    float4 a = fe[k], b = wr[k];
    s += a.x*b.x + a.y*b.y + a.z*b.z + a.w*b.w;
  }
  float* dst = (part==0)?Qm:((part==1)?Km:Vm);
  dst[l*256+d] = s;
}

// ---------------- stage 2: RNN FIRST (overlaps table builders) + coalesced tables ----------------
__global__ void k_pre2(const float* __restrict__ Qm, const float* __restrict__ Km,
                       const float* __restrict__ Vm,
                       const float* __restrict__ b_in, const float* __restrict__ W_ao,
                       const float* __restrict__ b_ao, const float* __restrict__ FE,
                       float* __restrict__ Gc, float* __restrict__ U,
                       float* __restrict__ W, float* __restrict__ S,
                       float* __restrict__ abias, short* __restrict__ M2c,
                       const float* __restrict__ W1, const float* __restrict__ W2,
                       short* __restrict__ W1c, short* __restrict__ W2c,
                       float* __restrict__ FEc,
                       const float* __restrict__ x_cont, const float* __restrict__ z0,
                       const float* __restrict__ W_ih, const float* __restrict__ W_hh,
                       const float* __restrict__ b_ih, const float* __restrict__ b_hh,
                       const float* __restrict__ Uf, const float* __restrict__ Wfp,
                       const float* __restrict__ bfp, float* __restrict__ zout){
  int bid = blockIdx.x;
  int tid = threadIdx.x;
  // attention tables pre-scaled by log2(e): softmax runs in exp2 domain
  const float inv = 0.17677669529663687f * 1.4426950408889634f;
  if (bid < 16){
    // ---- RNN: blocks 0..15, lanes 0..63 active ----
    int b = bid;
    int l = tid;
    bool act = (l < 64);
    __shared__ float h_sh[64];
    __shared__ float fh_sh[24];
    __shared__ float WfpT[24][64];
    float wr[64];
    float wih=0, bb=0, bf=0;
    float uf0=0,uf1=0,uf2=0,uf3=0;
    if (act){
      #pragma unroll
      for (int j=0;j<64;j++) wr[j] = W_hh[l*64+j];
      #pragma unroll
      for (int j=0;j<24;j++) WfpT[j][l] = Wfp[l*24+j];
      wih = W_ih[l];
      bb  = b_ih[l] + b_hh[l];
      bf  = bfp[l];
      if (l < 24){ uf0=Uf[l*4+0]; uf1=Uf[l*4+1]; uf2=Uf[l*4+2]; uf3=Uf[l*4+3]; }
      h_sh[l] = z0[l];
    }
    __syncthreads();
    const float* xb = x_cont + (size_t)b*128*97;
    for (int t=0;t<128;t++){
      float hn = 0.f, fh = 0.f;
      if (act){
        float x0 = xb[t*97];
        float a0=0,a1=0,a2=0,a3=0;
        #pragma unroll
        for (int j=0;j<64;j+=4){
          a0 += wr[j  ]*h_sh[j  ];
          a1 += wr[j+1]*h_sh[j+1];
          a2 += wr[j+2]*h_sh[j+2];
          a3 += wr[j+3]*h_sh[j+3];
        }
        hn = fmaxf(x0*wih + bb + ((a0+a1)+(a2+a3)), 0.f);
        if (l < 24){
          const float* xf = xb + t*97 + 1 + l*4;
          fh = xf[0]*uf0 + xf[1]*uf1 + xf[2]*uf2 + xf[3]*uf3;
        }
      }
      __syncthreads();
      if (act){
        h_sh[l] = hn;
        if (l < 24) fh_sh[l] = fh;
      }
      __syncthreads();
      if (act){
        float zv = hn + bf;
        #pragma unroll
        for (int j=0;j<24;j++) zv += fh_sh[j]*WfpT[j][l];
        zout[((size_t)b*128 + t)*64 + l] = zv;
      }
    }
    return;
  }
  if (bid < 214){
    int id = (bid-16)*256 + tid;
    if (id < 32768){
      int h = id >> 12, ks = (id>>11)&1, w4 = (id>>9)&3, lane = (id>>3)&63, j = id&7;
      int lq = w4*16 + (lane&15);
      int lk = ks*32 + (lane>>4)*8 + j;
      const float* qp = Qm + lq*256 + h*32;
      const float* kp = Km + lk*256 + h*32;
      float s=0.f;
      #pragma unroll
      for (int d=0;d<32;d++) s += qp[d]*kp[d];
      Gc[id] = s*inv;
    } else if (id < 33280){
      int j = id - 32768; int h = j>>6, lq = j&63;
      const float* qp = Qm + lq*256 + h*32;
      const float* bk = b_in + 256 + h*32;
      float s=0.f;
      #pragma unroll
      for (int d=0;d<32;d++) s += qp[d]*bk[d];
      U[j] = s*inv;
    } else if (id < 33792){
      int j = id - 33280; int h = j>>6, lk = j&63;
      const float* kp = Km + lk*256 + h*32;
      const float* bq = b_in + h*32;
      float s=0.f;
      #pragma unroll
      for (int d=0;d<32;d++) s += bq[d]*kp[d];
      W[j] = s*inv;
    } else if (id < 33800){
      int h = id - 33792;
      float s=0.f;
      #pragma unroll
      for (int d=0;d<32;d++) s += b_in[h*32+d]*b_in[256+h*32+d];
      S[h] = s*inv;
    } else if (id < 34056){
      int e = id - 33800;
      float s = b_ao[e];
      for (int d=0; d<256; d++) s += b_in[512+d]*W_ao[e*256+d];
      abias[e] = s;
    } else if (id < 50440){
      int o = id - 34056;
      int tt = o>>12, et = (o>>10)&3, w4 = (o>>8)&3, lane = (o>>2)&63, j = o&3;
      int row = tt*16 + (lane&15);
      int col = w4*64 + et*16 + (lane>>4)*4 + j;
      FEc[o] = FE[row*256 + col];
    }
    return;
  }
  if (bid < 726){
    int o = (bid-214)*256 + tid;
    int h = o>>14, ks = (o>>13)&1, w4 = (o>>11)&3, et = (o>>9)&3, lane = (o>>3)&63, j = o&7;
    int e = w4*64 + et*16 + (lane&15);
    int lk = ks*32 + (lane>>4)*8 + j;
    const float* vp = Vm + lk*256 + h*32;
    const float* wp = W_ao + e*256 + h*32;
    float s=0.f;
    #pragma unroll
    for (int d=0;d<32;d++) s += vp[d]*wp[d];
    M2c[o] = (short)f2b(s);
    return;
  }
  {
    // W1c/W2c: coalesced linear read, scattered write
    int id3 = (bid-726)*256 + tid;
    if (id3 < 262144){
      int row = id3 >> 8, col = id3 & 255;       // W1[1024][256]
      int c = row >> 7, w4 = (row>>5)&3, ct = (row>>4)&1, lrow = row & 15;
      int ks = col >> 5, lhi = (col>>3)&3, j = col & 7;
      int o = c*32768 + ks*4096 + w4*1024 + ct*512 + (lhi*16+lrow)*8 + j;
      W1c[o] = (short)f2b(W1[id3]);
    } else {
      int idx = id3 - 262144;
      int row = idx >> 10, col = idx & 1023;     // W2[256][1024]
      int w4 = row >> 6, et = (row>>4)&3, lrow = row & 15;
      int c = col >> 7, ks2 = (col>>5)&3, lhi = (col>>3)&3, j = col & 7;
      int o = c*32768 + ks2*8192 + w4*2048 + et*512 + (lhi*16+lrow)*8 + j;
      W2c[o] = (short)f2b(W2[idx]);
    }
    return;
  }
}

// ---------------- fused per-token transformer block (2048 blocks x 256 thr) ----------------
// 3 blocks/CU; exp2 softmax WITHOUT max-subtraction (|logit| ~ O(1), exp2 safe);
// gate dot distributed over all 256 threads.
__global__ __launch_bounds__(256, 3) void k_main(
  const float* __restrict__ zall, const float* __restrict__ Gc,
  const float* __restrict__ Ubuf, const float* __restrict__ Wbuf, const float* __restrict__ Sbuf,
  const float* __restrict__ abias, const short* __restrict__ M2c,
  const float* __restrict__ FEc,
  const short* __restrict__ W1c, const float* __restrict__ b1,
  const short* __restrict__ W2c, const float* __restrict__ b2,
  const float* __restrict__ g1, const float* __restrict__ be1,
  const float* __restrict__ g2, const float* __restrict__ be2,
  const float* __restrict__ Wop, const float* __restrict__ bop,
  const float* __restrict__ Wg, const float* __restrict__ bg,
  const float* __restrict__ Amat, const float* __restrict__ cvec,
  float* __restrict__ out)
{
  const int n = blockIdx.x;
  const int tid = threadIdx.x;
  const int w = tid >> 6, lane = tid & 63, lg = lane >> 4, lr = lane & 15;
  const int cb = w * 64;

  __shared__ __align__(16) short t1_sh[64][264];   // 33792 B
  __shared__ __align__(16) char  upool[17408];     // union: mid[64][136] | pa[2][4][2][64][8]
  __shared__ float redA[4][64];
  __shared__ float redB[4][64];
  __shared__ float gate_sh[64];
  __shared__ float z_sh[64];                       // 53760 B -> 3 blocks/CU

  short (*mid_sh)[136] = reinterpret_cast<short (*)[136]>(upool);
  short (*pa_sh)[4][2][64][8] = reinterpret_cast<short (*)[4][2][64][8]>(upool);

  if (tid < 64) z_sh[tid] = zall[n*64 + tid];
  __syncthreads();   // Z0

  float zkf[16];
  #pragma unroll
  for (int i=0;i<16;i++) zkf[i] = z_sh[(i>>3)*32 + lg*8 + (i&7)];

  // gate = sigmoid(z @ Wg^T + bg): 4 lanes per row, all 256 threads
  {
    const int glq = tid >> 2, gq = tid & 3;
    float p = 0.f;
    const f32x4* wg = (const f32x4*)(Wg + glq*64 + gq*16);
    const f32x4* zv4 = (const f32x4*)(z_sh + gq*16);
    #pragma unroll
    for (int i=0;i<4;i++){
      f32x4 wv = wg[i], zv = zv4[i];
      p += wv[0]*zv[0] + wv[1]*zv[1] + wv[2]*zv[2] + wv[3]*zv[3];
    }
    p += __shfl_xor(p, 1);
    p += __shfl_xor(p, 2);
    if (gq == 0) gate_sh[glq] = 1.f/(1.f + __expf(-(p + bg[glq])));
  }

  // shared accumulator: attention acc, later reused as FFN outv (64 AGPR total)
  f32x4 acc[4][4];
  #pragma unroll
  for (int et=0;et<4;et++)
    #pragma unroll
    for (int tt=0;tt<4;tt++){ f32x4 zz = {0.f,0.f,0.f,0.f}; acc[et][tt] = zz; }

  const int lq_own = w*16 + lr;
  const float zq_own = z_sh[lq_own];
  float zqzk[16];
  #pragma unroll
  for (int i=0;i<16;i++) zqzk[i] = zq_own * zkf[i];

  #pragma unroll 1
  for (int h=0; h<8; ++h){
    // --- softmax (exp2 domain, no max-sub: |logit| = O(1)) for rows of quarter tt==w ---
    {
      const float base = zq_own * Ubuf[h*64 + lq_own] + Sbuf[h];
      float e0[16];
      #pragma unroll
      for (int ks=0;ks<2;ks++){
        const float* gbase = Gc + h*4096 + ks*2048 + w*512 + lane*8;
        f32x4 ga = *(const f32x4*)(gbase);
        f32x4 gb = *(const f32x4*)(gbase + 4);
        f32x4 wa = *(const f32x4*)(Wbuf + h*64 + ks*32 + lg*8);
        f32x4 wb = *(const f32x4*)(Wbuf + h*64 + ks*32 + lg*8 + 4);
        #pragma unroll
        for (int j=0;j<4;j++){
          e0[ks*8+j]   = exp2f(fmaf(zqzk[ks*8+j],   ga[j], fmaf(zkf[ks*8+j],   wa[j], base)));
          e0[ks*8+4+j] = exp2f(fmaf(zqzk[ks*8+4+j], gb[j], fmaf(zkf[ks*8+4+j], wb[j], base)));
        }
      }
      float sum = 0.f;
      #pragma unroll
      for (int i=0;i<16;i++) sum += e0[i];
      sum += __shfl_xor(sum,16);
      sum += __shfl_xor(sum,32);
      float inv = __builtin_amdgcn_rcpf(sum);
      #pragma unroll
      for (int ks=0;ks<2;ks++){
        union { bf16x8 v; unsigned u[4]; } pa;
        #pragma unroll
        for (int p=0;p<4;p++)
          pa.u[p] = pk2(e0[ks*8+2*p]*inv*zkf[ks*8+2*p], e0[ks*8+2*p+1]*inv*zkf[ks*8+2*p+1]);
        *(bf16x8*)&pa_sh[h&1][w][ks][lane][0] = pa.v;
      }
    }
    __syncthreads();   // pa[h&1] ready
    __builtin_amdgcn_s_setprio(1);
    #pragma unroll
    for (int ks=0; ks<2; ks++){
      bf16x8 am[4], bt[4];
      #pragma unroll
      for (int et=0;et<4;et++)
        am[et] = *(const bf16x8*)(M2c + h*16384 + ks*8192 + w*2048 + et*512 + lane*8);
      #pragma unroll
      for (int tt=0;tt<4;tt++) bt[tt] = *(const bf16x8*)&pa_sh[h&1][tt][ks][lane][0];
      #pragma unroll
      for (int et=0;et<4;et++)
        #pragma unroll
        for (int tt=0;tt<4;tt++)
          acc[et][tt] = __builtin_amdgcn_mfma_f32_16x16x32_bf16(am[et], bt[tt], acc[et][tt], 0,0,0);
    }
    __builtin_amdgcn_s_setprio(0);
  }

  // ---------- t1 = LN(tokens + aop) ----------
  f32x4 ab4[4], g14[4], be14[4];
  #pragma unroll
  for (int et=0;et<4;et++){
    int e0_ = cb + et*16 + lg*4;
    ab4[et]  = *(const f32x4*)(abias + e0_);
    g14[et]  = *(const f32x4*)(g1 + e0_);
    be14[et] = *(const f32x4*)(be1 + e0_);
  }
  float sum1[4], ssq1[4];
  #pragma unroll
  for (int tt=0;tt<4;tt++){
    int tok = tt*16 + lr;
    float zt = z_sh[tok];
    float s = 0.f, sq = 0.f;
    #pragma unroll
    for (int et=0;et<4;et++){
      f32x4 fe = *(const f32x4*)(FEc + tt*4096 + et*1024 + w*256 + lane*4);
      #pragma unroll
      for (int r=0;r<4;r++){
        float v = acc[et][tt][r] + ab4[et][r] + zt*fe[r];
        acc[et][tt][r] = v; s += v; sq += v*v;
      }
    }
    s  += __shfl_xor(s,16);  s  += __shfl_xor(s,32);
    sq += __shfl_xor(sq,16); sq += __shfl_xor(sq,32);
    sum1[tt] = s; ssq1[tt] = sq;
  }
  if (lane < 16){
    #pragma unroll
    for (int tt=0;tt<4;tt++){ redA[w][tt*16+lane] = sum1[tt]; redB[w][tt*16+lane] = ssq1[tt]; }
  }
  __syncthreads();   // S1
  float mu1[4], rs1[4];
  #pragma unroll
  for (int tt=0;tt<4;tt++){
    int tok = tt*16 + lr;
    float s  = redA[0][tok] + redA[1][tok] + redA[2][tok] + redA[3][tok];
    float sq = redB[0][tok] + redB[1][tok] + redB[2][tok] + redB[3][tok];
    float m = s * (1.f/256.f);
    mu1[tt] = m;
    rs1[tt] = rsqrtf(sq*(1.f/256.f) - m*m + 1e-5f);
  }
  #pragma unroll
  for (int et=0;et<4;et++)
    #pragma unroll
    for (int tt=0;tt<4;tt++){
      uint2 p;
      float v0 = (acc[et][tt][0]-mu1[tt])*rs1[tt]*g14[et][0] + be14[et][0];
      float v1 = (acc[et][tt][1]-mu1[tt])*rs1[tt]*g14[et][1] + be14[et][1];
      float v2 = (acc[et][tt][2]-mu1[tt])*rs1[tt]*g14[et][2] + be14[et][2];
      float v3 = (acc[et][tt][3]-mu1[tt])*rs1[tt]*g14[et][3] + be14[et][3];
      p.x = pk2(v0,v1); p.y = pk2(v2,v3);
      *(uint2*)&t1_sh[tt*16+lr][cb + et*16 + lg*4] = p;
    }
  __syncthreads();   // T1 (last pa reads done -> upool reusable as mid)

  // ---------- FFN: 8 chunks, single mid, 2 barriers/chunk (acc reused as outv) ----------
  #pragma unroll
  for (int et=0;et<4;et++)
    #pragma unroll
    for (int tt=0;tt<4;tt++){ f32x4 zz = {0.f,0.f,0.f,0.f}; acc[et][tt] = zz; }

  #pragma unroll 1
  for (int c=0; c<8; c++){
    f32x4 midv[2][4];
    #pragma unroll
    for (int ct=0;ct<2;ct++){
      f32x4 bi = *(const f32x4*)(b1 + c*128 + w*32 + ct*16 + lg*4);
      #pragma unroll
      for (int tt=0;tt<4;tt++) midv[ct][tt] = bi;
    }
    #pragma unroll
    for (int ks=0; ks<8; ks++){
      bf16x8 bt[4], aw[2];
      #pragma unroll
      for (int tt=0;tt<4;tt++) bt[tt] = *(const bf16x8*)&t1_sh[tt*16+lr][ks*32 + lg*8];
      #pragma unroll
      for (int ct=0;ct<2;ct++)
        aw[ct] = *(const bf16x8*)(W1c + c*32768 + ks*4096 + w*1024 + ct*512 + lane*8);
      #pragma unroll
      for (int ct=0;ct<2;ct++)
        #pragma unroll
        for (int tt=0;tt<4;tt++)
          midv[ct][tt] = __builtin_amdgcn_mfma_f32_16x16x32_bf16(aw[ct], bt[tt], midv[ct][tt], 0,0,0);
    }
    __syncthreads();       // prior FFN2 reads of mid done
    #pragma unroll
    for (int ct=0;ct<2;ct++)
      #pragma unroll
      for (int tt=0;tt<4;tt++){
        uint2 p;
        p.x = pk2(fmaxf(midv[ct][tt][0],0.f), fmaxf(midv[ct][tt][1],0.f));
        p.y = pk2(fmaxf(midv[ct][tt][2],0.f), fmaxf(midv[ct][tt][3],0.f));
        *(uint2*)&mid_sh[tt*16+lr][w*32 + ct*16 + lg*4] = p;
      }
    __syncthreads();
    __builtin_amdgcn_s_setprio(1);
    #pragma unroll
    for (int ks2=0; ks2<4; ks2++){
      bf16x8 aw2[4], bm[4];
      #pragma unroll
      for (int et=0;et<4;et++)
        aw2[et] = *(const bf16x8*)(W2c + c*32768 + ks2*8192 + w*2048 + et*512 + lane*8);
      #pragma unroll
      for (int tt=0;tt<4;tt++) bm[tt] = *(const bf16x8*)&mid_sh[tt*16+lr][ks2*32 + lg*8];
      #pragma unroll
      for (int et=0;et<4;et++)
        #pragma unroll
        for (int tt=0;tt<4;tt++)
          acc[et][tt] = __builtin_amdgcn_mfma_f32_16x16x32_bf16(aw2[et], bm[tt], acc[et][tt], 0,0,0);
    }
    __builtin_amdgcn_s_setprio(0);
  }

  // ---------- t2 = LN(t1 + ffn), delta, z_out, o ----------
  f32x4 b24[4], g24[4], be24[4], wop4[4];
  #pragma unroll
  for (int et=0;et<4;et++){
    int e0_ = cb + et*16 + lg*4;
    b24[et]  = *(const f32x4*)(b2 + e0_);
    g24[et]  = *(const f32x4*)(g2 + e0_);
    be24[et] = *(const f32x4*)(be2 + e0_);
    wop4[et] = *(const f32x4*)(Wop + e0_);
  }
  float sum2[4], ssq2[4];
  #pragma unroll
  for (int tt=0;tt<4;tt++){
    int tok = tt*16 + lr;
    float s = 0.f, sq = 0.f;
    #pragma unroll
    for (int et=0;et<4;et++){
      uint2 t1v = *(const uint2*)&t1_sh[tok][cb + et*16 + lg*4];
      #pragma unroll
      for (int r=0;r<4;r++){
        unsigned short hs = (unsigned short)((r&1) ? ((r<2?t1v.x:t1v.y)>>16) : ((r<2?t1v.x:t1v.y)&0xFFFF));
        float v = acc[et][tt][r] + b24[et][r] + b2f(hs);
        acc[et][tt][r] = v; s += v; sq += v*v;
      }
    }
    s  += __shfl_xor(s,16);  s  += __shfl_xor(s,32);
    sq += __shfl_xor(sq,16); sq += __shfl_xor(sq,32);
    sum2[tt] = s; ssq2[tt] = sq;
  }
  if (lane < 16){
    #pragma unroll
    for (int tt=0;tt<4;tt++){ redA[w][tt*16+lane] = sum2[tt]; redB[w][tt*16+lane] = ssq2[tt]; }
  }
  __syncthreads();   // B2

  float dpart[4];
  #pragma unroll
  for (int tt=0;tt<4;tt++){
    int tok = tt*16 + lr;
    float s  = redA[0][tok] + redA[1][tok] + redA[2][tok] + redA[3][tok];
    float sq = redB[0][tok] + redB[1][tok] + redB[2][tok] + redB[3][tok];
    float m = s * (1.f/256.f);
    float rs = rsqrtf(sq*(1.f/256.f) - m*m + 1e-5f);
    float d = 0.f;
    #pragma unroll
    for (int et=0;et<4;et++)
      #pragma unroll
      for (int r=0;r<4;r++){
        float t2 = (acc[et][tt][r]-m)*rs*g24[et][r] + be24[et][r];
        d += t2*wop4[et][r];
      }
    d += __shfl_xor(d,16); d += __shfl_xor(d,32);
    dpart[tt] = d;
  }
  __syncthreads();   // N1
  if (lane < 16){
    #pragma unroll
    for (int tt=0;tt<4;tt++) redA[w][tt*16+lane] = dpart[tt];
  }
  __syncthreads();   // D2
  if (tid < 64){
    float delta = redA[0][tid]+redA[1][tid]+redA[2][tid]+redA[3][tid] + bop[0];
    float zo = z_sh[tid] + gate_sh[tid]*delta;
    out[49152 + (size_t)n*64 + tid] = zo;
    z_sh[tid] = zo;
  }
  __syncthreads();   // E2
  if (tid < 24){
    const float* ar = Amat + tid*64;
    float s = cvec[tid];
    #pragma unroll
    for (int j=0;j<64;j++) s += z_sh[j]*ar[j];
    out[(size_t)n*24 + tid] = s;
  }
}

extern "C" void kernel_launch(void* const* d_in, const int* in_sizes, int n_in,
                              void* d_out, int out_size, void* d_ws, size_t ws_size,
                              hipStream_t stream) {
  const float* x_cont = (const float*)d_in[0];
  const float* z0    = (const float*)d_in[1];
  const float* W_ih  = (const float*)d_in[2];
  const float* W_hh  = (const float*)d_in[3];
  const float* b_ih  = (const float*)d_in[4];
  const float* b_hh  = (const float*)d_in[5];
  const float* Uf    = (const float*)d_in[6];
  const float* Wfp   = (const float*)d_in[7];
  const float* bfp   = (const float*)d_in[8];
  const float* FE    = (const float*)d_in[9];
  const float* W_in  = (const float*)d_in[10];
  const float* b_in  = (const float*)d_in[11];
  const float* W_ao  = (const float*)d_in[12];
  const float* b_ao  = (const float*)d_in[13];
  const float* g1    = (const float*)d_in[14];
  const float* be1   = (const float*)d_in[15];
  const float* W1    = (const float*)d_in[16];
  const float* b1    = (const float*)d_in[17];
  const float* W2    = (const float*)d_in[18];
  const float* b2    = (const float*)d_in[19];
  const float* g2    = (const float*)d_in[20];
  const float* be2   = (const float*)d_in[21];
  const float* Wop   = (const float*)d_in[22];
  const float* bop   = (const float*)d_in[23];
  const float* Wg    = (const float*)d_in[24];
  const float* bg    = (const float*)d_in[25];
  const float* Amat  = (const float*)d_in[26];
  const float* cvec  = (const float*)d_in[27];
  float* out = (float*)d_out;
  char* ws = (char*)d_ws;

  float* z    = (float*)(ws + 0);         // 524288
  float* Qm   = (float*)(ws + 524288);    // 65536
  float* Km   = (float*)(ws + 589824);
  float* Vm   = (float*)(ws + 655360);
  float* Gc   = (float*)(ws + 720896);    // 131072
  float* U    = (float*)(ws + 851968);    // 2048
  float* Wb   = (float*)(ws + 854016);    // 2048
  float* S    = (float*)(ws + 856064);    // 256
  float* ab   = (float*)(ws + 856320);    // 1024
  short* M2c  = (short*)(ws + 857344);    // 262144
  short* W1c  = (short*)(ws + 1119488);   // 524288
  short* W2c  = (short*)(ws + 1643776);   // 524288
  float* FEc  = (float*)(ws + 2168064);   // 65536

  hipLaunchKernelGGL(k_pre_qkv, dim3(192), dim3(256), 0, stream, FE, W_in, Qm, Km, Vm);
  hipLaunchKernelGGL(k_pre2, dim3(2774), dim3(256), 0, stream,
                     Qm, Km, Vm, b_in, W_ao, b_ao, FE, Gc, U, Wb, S, ab, M2c,
                     W1, W2, W1c, W2c, FEc,
                     x_cont, z0, W_ih, W_hh, b_ih, b_hh, Uf, Wfp, bfp, z);
  hipLaunchKernelGGL(k_main, dim3(2048), dim3(256), 0, stream, z, Gc, U, Wb, S, ab, M2c, FEc,
                     W1c, b1, W2c, b2, g1, be1, g2, be2, Wop, bop, Wg, bg, Amat, cvec, out);
}

// Round 15
// 292.054 us; speedup vs baseline: 1.1605x; 1.0875x over previous
//
#include <hip/hip_runtime.h>

typedef short bf16x8 __attribute__((ext_vector_type(8)));
typedef float f32x4  __attribute__((ext_vector_type(4)));

__device__ __forceinline__ unsigned short f2b(float f){
  union { float f; unsigned u; } v; v.f = f;
  unsigned r = v.u + 0x7FFFu + ((v.u >> 16) & 1u);
  return (unsigned short)(r >> 16);
}
__device__ __forceinline__ float b2f(unsigned short s){
  union { unsigned u; float f; } v; v.u = ((unsigned)s) << 16;
  return v.f;
}
__device__ __forceinline__ unsigned pk2(float lo, float hi){
  unsigned r;
  asm("v_cvt_pk_bf16_f32 %0, %1, %2" : "=v"(r) : "v"(lo), "v"(hi));
  return r;
}

// ---------------- stage 1: qkv GEMM (192 blocks) + RNN input precompute (512 blocks) ----------------
// pre[n][l] = x0*W_ih[l] + b_ih[l] + b_hh[l];  fz[n][l] = bfp[l] + sum_j fh[n][j]*Wfp[l][j]
// (both independent of the recurrent state -> hoisted off the serial RNN path)
__global__ void k_pre1(const float* __restrict__ FE, const float* __restrict__ W_in,
                       float* __restrict__ Qm, float* __restrict__ Km, float* __restrict__ Vm,
                       const float* __restrict__ x_cont,
                       const float* __restrict__ W_ih,
                       const float* __restrict__ b_ih, const float* __restrict__ b_hh,
                       const float* __restrict__ Uf, const float* __restrict__ Wfp,
                       const float* __restrict__ bfp,
                       float* __restrict__ preA, float* __restrict__ fzA){
  int bid = blockIdx.x;
  int tid = threadIdx.x;
  if (bid < 192){
    int id = bid*256 + tid;
    int part = id >> 14;
    int l = (id >> 8) & 63;
    int d = id & 255;
    const float4* fe = (const float4*)(FE + l*256);
    const float4* wr = (const float4*)(W_in + (part*256 + d)*256);
    float s = 0.f;
    #pragma unroll 8
    for (int k=0;k<64;k++){
      float4 a = fe[k], b = wr[k];
      s += a.x*b.x + a.y*b.y + a.z*b.z + a.w*b.w;
    }
    float* dst = (part==0)?Qm:((part==1)?Km:Vm);
    dst[l*256+d] = s;
    return;
  }
  {
    // 512 blocks x 4 tokens x 64 lanes
    int g = tid >> 6, l = tid & 63;
    int n = (bid-192)*4 + g;
    __shared__ float Wfp_sh[64][24];
    __shared__ float fh_sh[4][24];
    for (int i=tid; i<1536; i+=256) Wfp_sh[i/24][i%24] = Wfp[i];
    const float* xr = x_cont + (size_t)n*97;
    float x0 = xr[0];
    if (l < 24){
      float fh = xr[1+l*4]*Uf[l*4] + xr[2+l*4]*Uf[l*4+1] + xr[3+l*4]*Uf[l*4+2] + xr[4+l*4]*Uf[l*4+3];
      fh_sh[g][l] = fh;
    }
    __syncthreads();
    float s = bfp[l];
    #pragma unroll
    for (int j=0;j<24;j++) s += fh_sh[g][j]*Wfp_sh[l][j];
    fzA[(size_t)n*64 + l] = s;
    preA[(size_t)n*64 + l] = x0*W_ih[l] + b_ih[l] + b_hh[l];
  }
}

// ---------------- stage 2: lean RNN FIRST (overlaps table builders) + coalesced tables ----------------
__global__ void k_pre2(const float* __restrict__ Qm, const float* __restrict__ Km,
                       const float* __restrict__ Vm,
                       const float* __restrict__ b_in, const float* __restrict__ W_ao,
                       const float* __restrict__ b_ao, const float* __restrict__ FE,
                       float* __restrict__ Gc, float* __restrict__ U,
                       float* __restrict__ W, float* __restrict__ S,
                       float* __restrict__ abias, short* __restrict__ M2c,
                       const float* __restrict__ W1, const float* __restrict__ W2,
                       short* __restrict__ W1c, short* __restrict__ W2c,
                       float* __restrict__ FEc,
                       const float* __restrict__ z0, const float* __restrict__ W_hh,
                       const float* __restrict__ preA, const float* __restrict__ fzA,
                       float* __restrict__ zout){
  int bid = blockIdx.x;
  int tid = threadIdx.x;
  // attention tables pre-scaled by log2(e): softmax runs in exp2 domain
  const float inv = 0.17677669529663687f * 1.4426950408889634f;
  if (bid < 16){
    // ---- lean RNN: blocks 0..15, lanes 0..63 active ----
    int b = bid;
    int l = tid;
    bool act = (l < 64);
    __shared__ float h_sh[64];
    float wr[64];
    if (act){
      #pragma unroll
      for (int j=0;j<64;j++) wr[j] = W_hh[l*64+j];
      h_sh[l] = z0[l];
    }
    __syncthreads();
    const float* pb = preA + (size_t)b*128*64;
    const float* fb = fzA  + (size_t)b*128*64;
    float* zb = zout + (size_t)b*128*64;
    for (int t=0;t<128;t++){
      float hn = 0.f, fz = 0.f;
      if (act){
        float pre = pb[t*64 + l];
        fz = fb[t*64 + l];
        float a0=0,a1=0,a2=0,a3=0;
        #pragma unroll
        for (int j=0;j<64;j+=4){
          a0 += wr[j  ]*h_sh[j  ];
          a1 += wr[j+1]*h_sh[j+1];
          a2 += wr[j+2]*h_sh[j+2];
          a3 += wr[j+3]*h_sh[j+3];
        }
        hn = fmaxf(pre + ((a0+a1)+(a2+a3)), 0.f);
      }
      __syncthreads();
      if (act){
        h_sh[l] = hn;
      }
      __syncthreads();
      if (act) zb[t*64 + l] = hn + fz;
    }
    return;
  }
  if (bid < 214){
    int id = (bid-16)*256 + tid;
    if (id < 32768){
      int h = id >> 12, ks = (id>>11)&1, w4 = (id>>9)&3, lane = (id>>3)&63, j = id&7;
      int lq = w4*16 + (lane&15);
      int lk = ks*32 + (lane>>4)*8 + j;
      const float* qp = Qm + lq*256 + h*32;
      const float* kp = Km + lk*256 + h*32;
      float s=0.f;
      #pragma unroll
      for (int d=0;d<32;d++) s += qp[d]*kp[d];
      Gc[id] = s*inv;
    } else if (id < 33280){
      int j = id - 32768; int h = j>>6, lq = j&63;
      const float* qp = Qm + lq*256 + h*32;
      const float* bk = b_in + 256 + h*32;
      float s=0.f;
      #pragma unroll
      for (int d=0;d<32;d++) s += qp[d]*bk[d];
      U[j] = s*inv;
    } else if (id < 33792){
      int j = id - 33280; int h = j>>6, lk = j&63;
      const float* kp = Km + lk*256 + h*32;
      const float* bq = b_in + h*32;
      float s=0.f;
      #pragma unroll
      for (int d=0;d<32;d++) s += bq[d]*kp[d];
      W[j] = s*inv;
    } else if (id < 33800){
      int h = id - 33792;
      float s=0.f;
      #pragma unroll
      for (int d=0;d<32;d++) s += b_in[h*32+d]*b_in[256+h*32+d];
      S[h] = s*inv;
    } else if (id < 34056){
      int e = id - 33800;
      float s = b_ao[e];
      for (int d=0; d<256; d++) s += b_in[512+d]*W_ao[e*256+d];
      abias[e] = s;
    } else if (id < 50440){
      int o = id - 34056;
      int tt = o>>12, et = (o>>10)&3, w4 = (o>>8)&3, lane = (o>>2)&63, j = o&3;
      int row = tt*16 + (lane&15);
      int col = w4*64 + et*16 + (lane>>4)*4 + j;
      FEc[o] = FE[row*256 + col];
    }
    return;
  }
  if (bid < 726){
    int o = (bid-214)*256 + tid;
    int h = o>>14, ks = (o>>13)&1, w4 = (o>>11)&3, et = (o>>9)&3, lane = (o>>3)&63, j = o&7;
    int e = w4*64 + et*16 + (lane&15);
    int lk = ks*32 + (lane>>4)*8 + j;
    const float* vp = Vm + lk*256 + h*32;
    const float* wp = W_ao + e*256 + h*32;
    float s=0.f;
    #pragma unroll
    for (int d=0;d<32;d++) s += vp[d]*wp[d];
    M2c[o] = (short)f2b(s);
    return;
  }
  {
    // W1c/W2c: coalesced linear read, scattered write
    int id3 = (bid-726)*256 + tid;
    if (id3 < 262144){
      int row = id3 >> 8, col = id3 & 255;       // W1[1024][256]
      int c = row >> 7, w4 = (row>>5)&3, ct = (row>>4)&1, lrow = row & 15;
      int ks = col >> 5, lhi = (col>>3)&3, j = col & 7;
      int o = c*32768 + ks*4096 + w4*1024 + ct*512 + (lhi*16+lrow)*8 + j;
      W1c[o] = (short)f2b(W1[id3]);
    } else {
      int idx = id3 - 262144;
      int row = idx >> 10, col = idx & 1023;     // W2[256][1024]
      int w4 = row >> 6, et = (row>>4)&3, lrow = row & 15;
      int c = col >> 7, ks2 = (col>>5)&3, lhi = (col>>3)&3, j = col & 7;
      int o = c*32768 + ks2*8192 + w4*2048 + et*512 + (lhi*16+lrow)*8 + j;
      W2c[o] = (short)f2b(W2[idx]);
    }
    return;
  }
}

// ---------------- fused per-token transformer block (2048 blocks x 256 thr) ----------------
// (byte-identical to R14's k_main)
__global__ __launch_bounds__(256, 3) void k_main(
  const float* __restrict__ zall, const float* __restrict__ Gc,
  const float* __restrict__ Ubuf, const float* __restrict__ Wbuf, const float* __restrict__ Sbuf,
  const float* __restrict__ abias, const short* __restrict__ M2c,
  const float* __restrict__ FEc,
  const short* __restrict__ W1c, const float* __restrict__ b1,
  const short* __restrict__ W2c, const float* __restrict__ b2,
  const float* __restrict__ g1, const float* __restrict__ be1,
  const float* __restrict__ g2, const float* __restrict__ be2,
  const float* __restrict__ Wop, const float* __restrict__ bop,
  const float* __restrict__ Wg, const float* __restrict__ bg,
  const float* __restrict__ Amat, const float* __restrict__ cvec,
  float* __restrict__ out)
{
  const int n = blockIdx.x;
  const int tid = threadIdx.x;
  const int w = tid >> 6, lane = tid & 63, lg = lane >> 4, lr = lane & 15;
  const int cb = w * 64;

  __shared__ __align__(16) short t1_sh[64][264];   // 33792 B
  __shared__ __align__(16) char  upool[17408];     // union: mid[64][136] | pa[2][4][2][64][8]
  __shared__ float redA[4][64];
  __shared__ float redB[4][64];
  __shared__ float gate_sh[64];
  __shared__ float z_sh[64];                       // 53760 B -> 3 blocks/CU

  short (*mid_sh)[136] = reinterpret_cast<short (*)[136]>(upool);
  short (*pa_sh)[4][2][64][8] = reinterpret_cast<short (*)[4][2][64][8]>(upool);

  if (tid < 64) z_sh[tid] = zall[n*64 + tid];
  __syncthreads();   // Z0

  float zkf[16];
  #pragma unroll
  for (int i=0;i<16;i++) zkf[i] = z_sh[(i>>3)*32 + lg*8 + (i&7)];

  // gate = sigmoid(z @ Wg^T + bg): 4 lanes per row, all 256 threads
  {
    const int glq = tid >> 2, gq = tid & 3;
    float p = 0.f;
    const f32x4* wg = (const f32x4*)(Wg + glq*64 + gq*16);
    const f32x4* zv4 = (const f32x4*)(z_sh + gq*16);
    #pragma unroll
    for (int i=0;i<4;i++){
      f32x4 wv = wg[i], zv = zv4[i];
      p += wv[0]*zv[0] + wv[1]*zv[1] + wv[2]*zv[2] + wv[3]*zv[3];
    }
    p += __shfl_xor(p, 1);
    p += __shfl_xor(p, 2);
    if (gq == 0) gate_sh[glq] = 1.f/(1.f + __expf(-(p + bg[glq])));
  }

  // shared accumulator: attention acc, later reused as FFN outv (64 AGPR total)
  f32x4 acc[4][4];
  #pragma unroll
  for (int et=0;et<4;et++)
    #pragma unroll
    for (int tt=0;tt<4;tt++){ f32x4 zz = {0.f,0.f,0.f,0.f}; acc[et][tt] = zz; }

  const int lq_own = w*16 + lr;
  const float zq_own = z_sh[lq_own];
  float zqzk[16];
  #pragma unroll
  for (int i=0;i<16;i++) zqzk[i] = zq_own * zkf[i];

  #pragma unroll 1
  for (int h=0; h<8; ++h){
    // --- softmax (exp2 domain, no max-sub: |logit| = O(1)) for rows of quarter tt==w ---
    {
      const float base = zq_own * Ubuf[h*64 + lq_own] + Sbuf[h];
      float e0[16];
      #pragma unroll
      for (int ks=0;ks<2;ks++){
        const float* gbase = Gc + h*4096 + ks*2048 + w*512 + lane*8;
        f32x4 ga = *(const f32x4*)(gbase);
        f32x4 gb = *(const f32x4*)(gbase + 4);
        f32x4 wa = *(const f32x4*)(Wbuf + h*64 + ks*32 + lg*8);
        f32x4 wb = *(const f32x4*)(Wbuf + h*64 + ks*32 + lg*8 + 4);
        #pragma unroll
        for (int j=0;j<4;j++){
          e0[ks*8+j]   = exp2f(fmaf(zqzk[ks*8+j],   ga[j], fmaf(zkf[ks*8+j],   wa[j], base)));
          e0[ks*8+4+j] = exp2f(fmaf(zqzk[ks*8+4+j], gb[j], fmaf(zkf[ks*8+4+j], wb[j], base)));
        }
      }
      float sum = 0.f;
      #pragma unroll
      for (int i=0;i<16;i++) sum += e0[i];
      sum += __shfl_xor(sum,16);
      sum += __shfl_xor(sum,32);
      float inv = __builtin_amdgcn_rcpf(sum);
      #pragma unroll
      for (int ks=0;ks<2;ks++){
        union { bf16x8 v; unsigned u[4]; } pa;
        #pragma unroll
        for (int p=0;p<4;p++)
          pa.u[p] = pk2(e0[ks*8+2*p]*inv*zkf[ks*8+2*p], e0[ks*8+2*p+1]*inv*zkf[ks*8+2*p+1]);
        *(bf16x8*)&pa_sh[h&1][w][ks][lane][0] = pa.v;
      }
    }
    __syncthreads();   // pa[h&1] ready
    __builtin_amdgcn_s_setprio(1);
    #pragma unroll
    for (int ks=0; ks<2; ks++){
      bf16x8 am[4], bt[4];
      #pragma unroll
      for (int et=0;et<4;et++)
        am[et] = *(const bf16x8*)(M2c + h*16384 + ks*8192 + w*2048 + et*512 + lane*8);
      #pragma unroll
      for (int tt=0;tt<4;tt++) bt[tt] = *(const bf16x8*)&pa_sh[h&1][tt][ks][lane][0];
      #pragma unroll
      for (int et=0;et<4;et++)
        #pragma unroll
        for (int tt=0;tt<4;tt++)
          acc[et][tt] = __builtin_amdgcn_mfma_f32_16x16x32_bf16(am[et], bt[tt], acc[et][tt], 0,0,0);
    }
    __builtin_amdgcn_s_setprio(0);
  }

  // ---------- t1 = LN(tokens + aop) ----------
  f32x4 ab4[4], g14[4], be14[4];
  #pragma unroll
  for (int et=0;et<4;et++){
    int e0_ = cb + et*16 + lg*4;
    ab4[et]  = *(const f32x4*)(abias + e0_);
    g14[et]  = *(const f32x4*)(g1 + e0_);
    be14[et] = *(const f32x4*)(be1 + e0_);
  }
  float sum1[4], ssq1[4];
  #pragma unroll
  for (int tt=0;tt<4;tt++){
    int tok = tt*16 + lr;
    float zt = z_sh[tok];
    float s = 0.f, sq = 0.f;
    #pragma unroll
    for (int et=0;et<4;et++){
      f32x4 fe = *(const f32x4*)(FEc + tt*4096 + et*1024 + w*256 + lane*4);
      #pragma unroll
      for (int r=0;r<4;r++){
        float v = acc[et][tt][r] + ab4[et][r] + zt*fe[r];
        acc[et][tt][r] = v; s += v; sq += v*v;
      }
    }
    s  += __shfl_xor(s,16);  s  += __shfl_xor(s,32);
    sq += __shfl_xor(sq,16); sq += __shfl_xor(sq,32);
    sum1[tt] = s; ssq1[tt] = sq;
  }
  if (lane < 16){
    #pragma unroll
    for (int tt=0;tt<4;tt++){ redA[w][tt*16+lane] = sum1[tt]; redB[w][tt*16+lane] = ssq1[tt]; }
  }
  __syncthreads();   // S1
  float mu1[4], rs1[4];
  #pragma unroll
  for (int tt=0;tt<4;tt++){
    int tok = tt*16 + lr;
    float s  = redA[0][tok] + redA[1][tok] + redA[2][tok] + redA[3][tok];
    float sq = redB[0][tok] + redB[1][tok] + redB[2][tok] + redB[3][tok];
    float m = s * (1.f/256.f);
    mu1[tt] = m;
    rs1[tt] = rsqrtf(sq*(1.f/256.f) - m*m + 1e-5f);
  }
  #pragma unroll
  for (int et=0;et<4;et++)
    #pragma unroll
    for (int tt=0;tt<4;tt++){
      uint2 p;
      float v0 = (acc[et][tt][0]-mu1[tt])*rs1[tt]*g14[et][0] + be14[et][0];
      float v1 = (acc[et][tt][1]-mu1[tt])*rs1[tt]*g14[et][1] + be14[et][1];
      float v2 = (acc[et][tt][2]-mu1[tt])*rs1[tt]*g14[et][2] + be14[et][2];
      float v3 = (acc[et][tt][3]-mu1[tt])*rs1[tt]*g14[et][3] + be14[et][3];
      p.x = pk2(v0,v1); p.y = pk2(v2,v3);
      *(uint2*)&t1_sh[tt*16+lr][cb + et*16 + lg*4] = p;
    }
  __syncthreads();   // T1 (last pa reads done -> upool reusable as mid)

  // ---------- FFN: 8 chunks, single mid, 2 barriers/chunk (acc reused as outv) ----------
  #pragma unroll
  for (int et=0;et<4;et++)
    #pragma unroll
    for (int tt=0;tt<4;tt++){ f32x4 zz = {0.f,0.f,0.f,0.f}; acc[et][tt] = zz; }

  #pragma unroll 1
  for (int c=0; c<8; c++){
    f32x4 midv[2][4];
    #pragma unroll
    for (int ct=0;ct<2;ct++){
      f32x4 bi = *(const f32x4*)(b1 + c*128 + w*32 + ct*16 + lg*4);
      #pragma unroll
      for (int tt=0;tt<4;tt++) midv[ct][tt] = bi;
    }
    #pragma unroll
    for (int ks=0; ks<8; ks++){
      bf16x8 bt[4], aw[2];
      #pragma unroll
      for (int tt=0;tt<4;tt++) bt[tt] = *(const bf16x8*)&t1_sh[tt*16+lr][ks*32 + lg*8];
      #pragma unroll
      for (int ct=0;ct<2;ct++)
        aw[ct] = *(const bf16x8*)(W1c + c*32768 + ks*4096 + w*1024 + ct*512 + lane*8);
      #pragma unroll
      for (int ct=0;ct<2;ct++)
        #pragma unroll
        for (int tt=0;tt<4;tt++)
          midv[ct][tt] = __builtin_amdgcn_mfma_f32_16x16x32_bf16(aw[ct], bt[tt], midv[ct][tt], 0,0,0);
    }
    __syncthreads();       // prior FFN2 reads of mid done
    #pragma unroll
    for (int ct=0;ct<2;ct++)
      #pragma unroll
      for (int tt=0;tt<4;tt++){
        uint2 p;
        p.x = pk2(fmaxf(midv[ct][tt][0],0.f), fmaxf(midv[ct][tt][1],0.f));
        p.y = pk2(fmaxf(midv[ct][tt][2],0.f), fmaxf(midv[ct][tt][3],0.f));
        *(uint2*)&mid_sh[tt*16+lr][w*32 + ct*16 + lg*4] = p;
      }
    __syncthreads();
    __builtin_amdgcn_s_setprio(1);
    #pragma unroll
    for (int ks2=0; ks2<4; ks2++){
      bf16x8 aw2[4], bm[4];
      #pragma unroll
      for (int et=0;et<4;et++)
        aw2[et] = *(const bf16x8*)(W2c + c*32768 + ks2*8192 + w*2048 + et*512 + lane*8);
      #pragma unroll
      for (int tt=0;tt<4;tt++) bm[tt] = *(const bf16x8*)&mid_sh[tt*16+lr][ks2*32 + lg*8];
      #pragma unroll
      for (int et=0;et<4;et++)
        #pragma unroll
        for (int tt=0;tt<4;tt++)
          acc[et][tt] = __builtin_amdgcn_mfma_f32_16x16x32_bf16(aw2[et], bm[tt], acc[et][tt], 0,0,0);
    }
    __builtin_amdgcn_s_setprio(0);
  }

  // ---------- t2 = LN(t1 + ffn), delta, z_out, o ----------
  f32x4 b24[4], g24[4], be24[4], wop4[4];
  #pragma unroll
  for (int et=0;et<4;et++){
    int e0_ = cb + et*16 + lg*4;
    b24[et]  = *(const f32x4*)(b2 + e0_);
    g24[et]  = *(const f32x4*)(g2 + e0_);
    be24[et] = *(const f32x4*)(be2 + e0_);
    wop4[et] = *(const f32x4*)(Wop + e0_);
  }
  float sum2[4], ssq2[4];
  #pragma unroll
  for (int tt=0;tt<4;tt++){
    int tok = tt*16 + lr;
    float s = 0.f, sq = 0.f;
    #pragma unroll
    for (int et=0;et<4;et++){
      uint2 t1v = *(const uint2*)&t1_sh[tok][cb + et*16 + lg*4];
      #pragma unroll
      for (int r=0;r<4;r++){
        unsigned short hs = (unsigned short)((r&1) ? ((r<2?t1v.x:t1v.y)>>16) : ((r<2?t1v.x:t1v.y)&0xFFFF));
        float v = acc[et][tt][r] + b24[et][r] + b2f(hs);
        acc[et][tt][r] = v; s += v; sq += v*v;
      }
    }
    s  += __shfl_xor(s,16);  s  += __shfl_xor(s,32);
    sq += __shfl_xor(sq,16); sq += __shfl_xor(sq,32);
    sum2[tt] = s; ssq2[tt] = sq;
  }
  if (lane < 16){
    #pragma unroll
    for (int tt=0;tt<4;tt++){ redA[w][tt*16+lane] = sum2[tt]; redB[w][tt*16+lane] = ssq2[tt]; }
  }
  __syncthreads();   // B2

  float dpart[4];
  #pragma unroll
  for (int tt=0;tt<4;tt++){
    int tok = tt*16 + lr;
    float s  = redA[0][tok] + redA[1][tok] + redA[2][tok] + redA[3][tok];
    float sq = redB[0][tok] + redB[1][tok] + redB[2][tok] + redB[3][tok];
    float m = s * (1.f/256.f);
    float rs = rsqrtf(sq*(1.f/256.f) - m*m + 1e-5f);
    float d = 0.f;
    #pragma unroll
    for (int et=0;et<4;et++)
      #pragma unroll
      for (int r=0;r<4;r++){
        float t2 = (acc[et][tt][r]-m)*rs*g24[et][r] + be24[et][r];
        d += t2*wop4[et][r];
      }
    d += __shfl_xor(d,16); d += __shfl_xor(d,32);
    dpart[tt] = d;
  }
  __syncthreads();   // N1
  if (lane < 16){
    #pragma unroll
    for (int tt=0;tt<4;tt++) redA[w][tt*16+lane] = dpart[tt];
  }
  __syncthreads();   // D2
  if (tid < 64){
    float delta = redA[0][tid]+redA[1][tid]+redA[2][tid]+redA[3][tid] + bop[0];
    float zo = z_sh[tid] + gate_sh[tid]*delta;
    out[49152 + (size_t)n*64 + tid] = zo;
    z_sh[tid] = zo;
  }
  __syncthreads();   // E2
  if (tid < 24){
    const float* ar = Amat + tid*64;
    float s = cvec[tid];
    #pragma unroll
    for (int j=0;j<64;j++) s += z_sh[j]*ar[j];
    out[(size_t)n*24 + tid] = s;
  }
}

extern "C" void kernel_launch(void* const* d_in, const int* in_sizes, int n_in,
                              void* d_out, int out_size, void* d_ws, size_t ws_size,
                              hipStream_t stream) {
  const float* x_cont = (const float*)d_in[0];
  const float* z0    = (const float*)d_in[1];
  const float* W_ih  = (const float*)d_in[2];
  const float* W_hh  = (const float*)d_in[3];
  const float* b_ih  = (const float*)d_in[4];
  const float* b_hh  = (const float*)d_in[5];
  const float* Uf    = (const float*)d_in[6];
  const float* Wfp   = (const float*)d_in[7];
  const float* bfp   = (const float*)d_in[8];
  const float* FE    = (const float*)d_in[9];
  const float* W_in  = (const float*)d_in[10];
  const float* b_in  = (const float*)d_in[11];
  const float* W_ao  = (const float*)d_in[12];
  const float* b_ao  = (const float*)d_in[13];
  const float* g1    = (const float*)d_in[14];
  const float* be1   = (const float*)d_in[15];
  const float* W1    = (const float*)d_in[16];
  const float* b1    = (const float*)d_in[17];
  const float* W2    = (const float*)d_in[18];
  const float* b2    = (const float*)d_in[19];
  const float* g2    = (const float*)d_in[20];
  const float* be2   = (const float*)d_in[21];
  const float* Wop   = (const float*)d_in[22];
  const float* bop   = (const float*)d_in[23];
  const float* Wg    = (const float*)d_in[24];
  const float* bg    = (const float*)d_in[25];
  const float* Amat  = (const float*)d_in[26];
  const float* cvec  = (const float*)d_in[27];
  float* out = (float*)d_out;
  char* ws = (char*)d_ws;

  float* z    = (float*)(ws + 0);         // 524288
  float* Qm   = (float*)(ws + 524288);    // 65536
  float* Km   = (float*)(ws + 589824);
  float* Vm   = (float*)(ws + 655360);
  float* Gc   = (float*)(ws + 720896);    // 131072
  float* U    = (float*)(ws + 851968);    // 2048
  float* Wb   = (float*)(ws + 854016);    // 2048
  float* S    = (float*)(ws + 856064);    // 256
  float* ab   = (float*)(ws + 856320);    // 1024
  short* M2c  = (short*)(ws + 857344);    // 262144
  short* W1c  = (short*)(ws + 1119488);   // 524288
  short* W2c  = (short*)(ws + 1643776);   // 524288
  float* FEc  = (float*)(ws + 2168064);   // 65536
  float* preA = (float*)(ws + 2233600);   // 524288
  float* fzA  = (float*)(ws + 2757888);   // 524288  (end 3282176)

  hipLaunchKernelGGL(k_pre1, dim3(704), dim3(256), 0, stream,
                     FE, W_in, Qm, Km, Vm,
                     x_cont, W_ih, b_ih, b_hh, Uf, Wfp, bfp, preA, fzA);
  hipLaunchKernelGGL(k_pre2, dim3(2774), dim3(256), 0, stream,
                     Qm, Km, Vm, b_in, W_ao, b_ao, FE, Gc, U, Wb, S, ab, M2c,
                     W1, W2, W1c, W2c, FEc,
                     z0, W_hh, preA, fzA, z);
  hipLaunchKernelGGL(k_main, dim3(2048), dim3(256), 0, stream, z, Gc, U, Wb, S, ab, M2c, FEc,
                     W1c, b1, W2c, b2, g1, be1, g2, be2, Wop, bop, Wg, bg, Amat, cvec, out);
}

// Round 16
// 291.276 us; speedup vs baseline: 1.1636x; 1.0027x over previous
//
#include <hip/hip_runtime.h>

typedef short bf16x8 __attribute__((ext_vector_type(8)));
typedef float f32x4  __attribute__((ext_vector_type(4)));

__device__ __forceinline__ unsigned short f2b(float f){
  union { float f; unsigned u; } v; v.f = f;
  unsigned r = v.u + 0x7FFFu + ((v.u >> 16) & 1u);
  return (unsigned short)(r >> 16);
}
__device__ __forceinline__ float b2f(unsigned short s){
  union { unsigned u; float f; } v; v.u = ((unsigned)s) << 16;
  return v.f;
}
__device__ __forceinline__ unsigned pk2(float lo, float hi){
  unsigned r;
  asm("v_cvt_pk_bf16_f32 %0, %1, %2" : "=v"(r) : "v"(lo), "v"(hi));
  return r;
}

// ---------------- stage 1: qkv GEMM (192 blocks) + RNN input precompute (512 blocks) ----------------
__global__ void k_pre1(const float* __restrict__ FE, const float* __restrict__ W_in,
                       float* __restrict__ Qm, float* __restrict__ Km, float* __restrict__ Vm,
                       const float* __restrict__ x_cont,
                       const float* __restrict__ W_ih,
                       const float* __restrict__ b_ih, const float* __restrict__ b_hh,
                       const float* __restrict__ Uf, const float* __restrict__ Wfp,
                       const float* __restrict__ bfp,
                       float* __restrict__ preA, float* __restrict__ fzA){
  int bid = blockIdx.x;
  int tid = threadIdx.x;
  if (bid < 192){
    int id = bid*256 + tid;
    int part = id >> 14;
    int l = (id >> 8) & 63;
    int d = id & 255;
    const float4* fe = (const float4*)(FE + l*256);
    const float4* wr = (const float4*)(W_in + (part*256 + d)*256);
    float s = 0.f;
    #pragma unroll 8
    for (int k=0;k<64;k++){
      float4 a = fe[k], b = wr[k];
      s += a.x*b.x + a.y*b.y + a.z*b.z + a.w*b.w;
    }
    float* dst = (part==0)?Qm:((part==1)?Km:Vm);
    dst[l*256+d] = s;
    return;
  }
  {
    int g = tid >> 6, l = tid & 63;
    int n = (bid-192)*4 + g;
    __shared__ float Wfp_sh[64][24];
    __shared__ float fh_sh[4][24];
    for (int i=tid; i<1536; i+=256) Wfp_sh[i/24][i%24] = Wfp[i];
    const float* xr = x_cont + (size_t)n*97;
    float x0 = xr[0];
    if (l < 24){
      float fh = xr[1+l*4]*Uf[l*4] + xr[2+l*4]*Uf[l*4+1] + xr[3+l*4]*Uf[l*4+2] + xr[4+l*4]*Uf[l*4+3];
      fh_sh[g][l] = fh;
    }
    __syncthreads();
    float s = bfp[l];
    #pragma unroll
    for (int j=0;j<24;j++) s += fh_sh[g][j]*Wfp_sh[l][j];
    fzA[(size_t)n*64 + l] = s;
    preA[(size_t)n*64 + l] = x0*W_ih[l] + b_ih[l] + b_hh[l];
  }
}

// ---------------- stage 2: lean RNN FIRST (overlaps table builders) + coalesced tables ----------------
__global__ void k_pre2(const float* __restrict__ Qm, const float* __restrict__ Km,
                       const float* __restrict__ Vm,
                       const float* __restrict__ b_in, const float* __restrict__ W_ao,
                       const float* __restrict__ b_ao, const float* __restrict__ FE,
                       float* __restrict__ Gc, float* __restrict__ U,
                       float* __restrict__ W, float* __restrict__ S,
                       float* __restrict__ abias, short* __restrict__ M2c,
                       const float* __restrict__ W1, const float* __restrict__ W2,
                       short* __restrict__ W1c, short* __restrict__ W2c,
                       float* __restrict__ FEc,
                       const float* __restrict__ z0, const float* __restrict__ W_hh,
                       const float* __restrict__ preA, const float* __restrict__ fzA,
                       float* __restrict__ zout){
  int bid = blockIdx.x;
  int tid = threadIdx.x;
  const float inv = 0.17677669529663687f * 1.4426950408889634f;
  if (bid < 16){
    int b = bid;
    int l = tid;
    bool act = (l < 64);
    __shared__ float h_sh[64];
    float wr[64];
    if (act){
      #pragma unroll
      for (int j=0;j<64;j++) wr[j] = W_hh[l*64+j];
      h_sh[l] = z0[l];
    }
    __syncthreads();
    const float* pb = preA + (size_t)b*128*64;
    const float* fb = fzA  + (size_t)b*128*64;
    float* zb = zout + (size_t)b*128*64;
    for (int t=0;t<128;t++){
      float hn = 0.f, fz = 0.f;
      if (act){
        float pre = pb[t*64 + l];
        fz = fb[t*64 + l];
        float a0=0,a1=0,a2=0,a3=0;
        #pragma unroll
        for (int j=0;j<64;j+=4){
          a0 += wr[j  ]*h_sh[j  ];
          a1 += wr[j+1]*h_sh[j+1];
          a2 += wr[j+2]*h_sh[j+2];
          a3 += wr[j+3]*h_sh[j+3];
        }
        hn = fmaxf(pre + ((a0+a1)+(a2+a3)), 0.f);
      }
      __syncthreads();
      if (act){
        h_sh[l] = hn;
      }
      __syncthreads();
      if (act) zb[t*64 + l] = hn + fz;
    }
    return;
  }
  if (bid < 214){
    int id = (bid-16)*256 + tid;
    if (id < 32768){
      int h = id >> 12, ks = (id>>11)&1, w4 = (id>>9)&3, lane = (id>>3)&63, j = id&7;
      int lq = w4*16 + (lane&15);
      int lk = ks*32 + (lane>>4)*8 + j;
      const float* qp = Qm + lq*256 + h*32;
      const float* kp = Km + lk*256 + h*32;
      float s=0.f;
      #pragma unroll
      for (int d=0;d<32;d++) s += qp[d]*kp[d];
      Gc[id] = s*inv;
    } else if (id < 33280){
      int j = id - 32768; int h = j>>6, lq = j&63;
      const float* qp = Qm + lq*256 + h*32;
      const float* bk = b_in + 256 + h*32;
      float s=0.f;
      #pragma unroll
      for (int d=0;d<32;d++) s += qp[d]*bk[d];
      U[j] = s*inv;
    } else if (id < 33792){
      int j = id - 33280; int h = j>>6, lk = j&63;
      const float* kp = Km + lk*256 + h*32;
      const float* bq = b_in + h*32;
      float s=0.f;
      #pragma unroll
      for (int d=0;d<32;d++) s += bq[d]*kp[d];
      W[j] = s*inv;
    } else if (id < 33800){
      int h = id - 33792;
      float s=0.f;
      #pragma unroll
      for (int d=0;d<32;d++) s += b_in[h*32+d]*b_in[256+h*32+d];
      S[h] = s*inv;
    } else if (id < 34056){
      int e = id - 33800;
      float s = b_ao[e];
      for (int d=0; d<256; d++) s += b_in[512+d]*W_ao[e*256+d];
      abias[e] = s;
    } else if (id < 50440){
      int o = id - 34056;
      int tt = o>>12, et = (o>>10)&3, w4 = (o>>8)&3, lane = (o>>2)&63, j = o&3;
      int row = tt*16 + (lane&15);
      int col = w4*64 + et*16 + (lane>>4)*4 + j;
      FEc[o] = FE[row*256 + col];
    }
    return;
  }
  if (bid < 726){
    int o = (bid-214)*256 + tid;
    int h = o>>14, ks = (o>>13)&1, w4 = (o>>11)&3, et = (o>>9)&3, lane = (o>>3)&63, j = o&7;
    int e = w4*64 + et*16 + (lane&15);
    int lk = ks*32 + (lane>>4)*8 + j;
    const float* vp = Vm + lk*256 + h*32;
    const float* wp = W_ao + e*256 + h*32;
    float s=0.f;
    #pragma unroll
    for (int d=0;d<32;d++) s += vp[d]*wp[d];
    M2c[o] = (short)f2b(s);
    return;
  }
  {
    int id3 = (bid-726)*256 + tid;
    if (id3 < 262144){
      int row = id3 >> 8, col = id3 & 255;       // W1[1024][256]
      int c = row >> 7, w4 = (row>>5)&3, ct = (row>>4)&1, lrow = row & 15;
      int ks = col >> 5, lhi = (col>>3)&3, j = col & 7;
      int o = c*32768 + ks*4096 + w4*1024 + ct*512 + (lhi*16+lrow)*8 + j;
      W1c[o] = (short)f2b(W1[id3]);
    } else {
      int idx = id3 - 262144;
      int row = idx >> 10, col = idx & 1023;     // W2[256][1024]
      int w4 = row >> 6, et = (row>>4)&3, lrow = row & 15;
      int c = col >> 7, ks2 = (col>>5)&3, lhi = (col>>3)&3, j = col & 7;
      int o = c*32768 + ks2*8192 + w4*2048 + et*512 + (lhi*16+lrow)*8 + j;
      W2c[o] = (short)f2b(W2[idx]);
    }
    return;
  }
}

// ---------------- fused per-token transformer block (2048 blocks x 256 thr) ----------------
// R15 minus attention setprio: merges the MFMA cluster and next-head softmax into one
// scheduling region so LLVM can interleave VALU between MFMAs (intra-wave dual-pipe feed).
__global__ __launch_bounds__(256, 3) void k_main(
  const float* __restrict__ zall, const float* __restrict__ Gc,
  const float* __restrict__ Ubuf, const float* __restrict__ Wbuf, const float* __restrict__ Sbuf,
  const float* __restrict__ abias, const short* __restrict__ M2c,
  const float* __restrict__ FEc,
  const short* __restrict__ W1c, const float* __restrict__ b1,
  const short* __restrict__ W2c, const float* __restrict__ b2,
  const float* __restrict__ g1, const float* __restrict__ be1,
  const float* __restrict__ g2, const float* __restrict__ be2,
  const float* __restrict__ Wop, const float* __restrict__ bop,
  const float* __restrict__ Wg, const float* __restrict__ bg,
  const float* __restrict__ Amat, const float* __restrict__ cvec,
  float* __restrict__ out)
{
  const int n = blockIdx.x;
  const int tid = threadIdx.x;
  const int w = tid >> 6, lane = tid & 63, lg = lane >> 4, lr = lane & 15;
  const int cb = w * 64;

  __shared__ __align__(16) short t1_sh[64][264];   // 33792 B
  __shared__ __align__(16) char  upool[17408];     // union: mid[64][136] | pa[2][4][2][64][8]
  __shared__ float redA[4][64];
  __shared__ float redB[4][64];
  __shared__ float gate_sh[64];
  __shared__ float z_sh[64];                       // 53760 B -> 3 blocks/CU

  short (*mid_sh)[136] = reinterpret_cast<short (*)[136]>(upool);
  short (*pa_sh)[4][2][64][8] = reinterpret_cast<short (*)[4][2][64][8]>(upool);

  if (tid < 64) z_sh[tid] = zall[n*64 + tid];
  __syncthreads();   // Z0

  float zkf[16];
  #pragma unroll
  for (int i=0;i<16;i++) zkf[i] = z_sh[(i>>3)*32 + lg*8 + (i&7)];

  // gate = sigmoid(z @ Wg^T + bg): 4 lanes per row, all 256 threads
  {
    const int glq = tid >> 2, gq = tid & 3;
    float p = 0.f;
    const f32x4* wg = (const f32x4*)(Wg + glq*64 + gq*16);
    const f32x4* zv4 = (const f32x4*)(z_sh + gq*16);
    #pragma unroll
    for (int i=0;i<4;i++){
      f32x4 wv = wg[i], zv = zv4[i];
      p += wv[0]*zv[0] + wv[1]*zv[1] + wv[2]*zv[2] + wv[3]*zv[3];
    }
    p += __shfl_xor(p, 1);
    p += __shfl_xor(p, 2);
    if (gq == 0) gate_sh[glq] = 1.f/(1.f + __expf(-(p + bg[glq])));
  }

  // shared accumulator: attention acc, later reused as FFN outv (64 AGPR total)
  f32x4 acc[4][4];
  #pragma unroll
  for (int et=0;et<4;et++)
    #pragma unroll
    for (int tt=0;tt<4;tt++){ f32x4 zz = {0.f,0.f,0.f,0.f}; acc[et][tt] = zz; }

  const int lq_own = w*16 + lr;
  const float zq_own = z_sh[lq_own];
  float zqzk[16];
  #pragma unroll
  for (int i=0;i<16;i++) zqzk[i] = zq_own * zkf[i];

  #pragma unroll 1
  for (int h=0; h<8; ++h){
    // --- softmax (exp2 domain, no max-sub) for rows of quarter tt==w ---
    {
      const float base = zq_own * Ubuf[h*64 + lq_own] + Sbuf[h];
      float e0[16];
      #pragma unroll
      for (int ks=0;ks<2;ks++){
        const float* gbase = Gc + h*4096 + ks*2048 + w*512 + lane*8;
        f32x4 ga = *(const f32x4*)(gbase);
        f32x4 gb = *(const f32x4*)(gbase + 4);
        f32x4 wa = *(const f32x4*)(Wbuf + h*64 + ks*32 + lg*8);
        f32x4 wb = *(const f32x4*)(Wbuf + h*64 + ks*32 + lg*8 + 4);
        #pragma unroll
        for (int j=0;j<4;j++){
          e0[ks*8+j]   = exp2f(fmaf(zqzk[ks*8+j],   ga[j], fmaf(zkf[ks*8+j],   wa[j], base)));
          e0[ks*8+4+j] = exp2f(fmaf(zqzk[ks*8+4+j], gb[j], fmaf(zkf[ks*8+4+j], wb[j], base)));
        }
      }
      float sum = 0.f;
      #pragma unroll
      for (int i=0;i<16;i++) sum += e0[i];
      sum += __shfl_xor(sum,16);
      sum += __shfl_xor(sum,32);
      float inv = __builtin_amdgcn_rcpf(sum);
      #pragma unroll
      for (int ks=0;ks<2;ks++){
        union { bf16x8 v; unsigned u[4]; } pa;
        #pragma unroll
        for (int p=0;p<4;p++)
          pa.u[p] = pk2(e0[ks*8+2*p]*inv*zkf[ks*8+2*p], e0[ks*8+2*p+1]*inv*zkf[ks*8+2*p+1]);
        *(bf16x8*)&pa_sh[h&1][w][ks][lane][0] = pa.v;
      }
    }
    __syncthreads();   // pa[h&1] ready
    // MFMA cluster — no setprio: keep this and the NEXT iteration's softmax in one
    // scheduling region so VALU can interleave with MFMA issue.
    #pragma unroll
    for (int ks=0; ks<2; ks++){
      bf16x8 am[4], bt[4];
      #pragma unroll
      for (int et=0;et<4;et++)
        am[et] = *(const bf16x8*)(M2c + h*16384 + ks*8192 + w*2048 + et*512 + lane*8);
      #pragma unroll
      for (int tt=0;tt<4;tt++) bt[tt] = *(const bf16x8*)&pa_sh[h&1][tt][ks][lane][0];
      #pragma unroll
      for (int et=0;et<4;et++)
        #pragma unroll
        for (int tt=0;tt<4;tt++)
          acc[et][tt] = __builtin_amdgcn_mfma_f32_16x16x32_bf16(am[et], bt[tt], acc[et][tt], 0,0,0);
    }
  }

  // ---------- t1 = LN(tokens + aop) ----------
  f32x4 ab4[4], g14[4], be14[4];
  #pragma unroll
  for (int et=0;et<4;et++){
    int e0_ = cb + et*16 + lg*4;
    ab4[et]  = *(const f32x4*)(abias + e0_);
    g14[et]  = *(const f32x4*)(g1 + e0_);
    be14[et] = *(const f32x4*)(be1 + e0_);
  }
  float sum1[4], ssq1[4];
  #pragma unroll
  for (int tt=0;tt<4;tt++){
    int tok = tt*16 + lr;
    float zt = z_sh[tok];
    float s = 0.f, sq = 0.f;
    #pragma unroll
    for (int et=0;et<4;et++){
      f32x4 fe = *(const f32x4*)(FEc + tt*4096 + et*1024 + w*256 + lane*4);
      #pragma unroll
      for (int r=0;r<4;r++){
        float v = acc[et][tt][r] + ab4[et][r] + zt*fe[r];
        acc[et][tt][r] = v; s += v; sq += v*v;
      }
    }
    s  += __shfl_xor(s,16);  s  += __shfl_xor(s,32);
    sq += __shfl_xor(sq,16); sq += __shfl_xor(sq,32);
    sum1[tt] = s; ssq1[tt] = sq;
  }
  if (lane < 16){
    #pragma unroll
    for (int tt=0;tt<4;tt++){ redA[w][tt*16+lane] = sum1[tt]; redB[w][tt*16+lane] = ssq1[tt]; }
  }
  __syncthreads();   // S1
  float mu1[4], rs1[4];
  #pragma unroll
  for (int tt=0;tt<4;tt++){
    int tok = tt*16 + lr;
    float s  = redA[0][tok] + redA[1][tok] + redA[2][tok] + redA[3][tok];
    float sq = redB[0][tok] + redB[1][tok] + redB[2][tok] + redB[3][tok];
    float m = s * (1.f/256.f);
    mu1[tt] = m;
    rs1[tt] = rsqrtf(sq*(1.f/256.f) - m*m + 1e-5f);
  }
  #pragma unroll
  for (int et=0;et<4;et++)
    #pragma unroll
    for (int tt=0;tt<4;tt++){
      uint2 p;
      float v0 = (acc[et][tt][0]-mu1[tt])*rs1[tt]*g14[et][0] + be14[et][0];
      float v1 = (acc[et][tt][1]-mu1[tt])*rs1[tt]*g14[et][1] + be14[et][1];
      float v2 = (acc[et][tt][2]-mu1[tt])*rs1[tt]*g14[et][2] + be14[et][2];
      float v3 = (acc[et][tt][3]-mu1[tt])*rs1[tt]*g14[et][3] + be14[et][3];
      p.x = pk2(v0,v1); p.y = pk2(v2,v3);
      *(uint2*)&t1_sh[tt*16+lr][cb + et*16 + lg*4] = p;
    }
  __syncthreads();   // T1 (last pa reads done -> upool reusable as mid)

  // ---------- FFN: 8 chunks, single mid, 2 barriers/chunk (acc reused as outv) ----------
  #pragma unroll
  for (int et=0;et<4;et++)
    #pragma unroll
    for (int tt=0;tt<4;tt++){ f32x4 zz = {0.f,0.f,0.f,0.f}; acc[et][tt] = zz; }

  #pragma unroll 1
  for (int c=0; c<8; c++){
    f32x4 midv[2][4];
    #pragma unroll
    for (int ct=0;ct<2;ct++){
      f32x4 bi = *(const f32x4*)(b1 + c*128 + w*32 + ct*16 + lg*4);
      #pragma unroll
      for (int tt=0;tt<4;tt++) midv[ct][tt] = bi;
    }
    #pragma unroll
    for (int ks=0; ks<8; ks++){
      bf16x8 bt[4], aw[2];
      #pragma unroll
      for (int tt=0;tt<4;tt++) bt[tt] = *(const bf16x8*)&t1_sh[tt*16+lr][ks*32 + lg*8];
      #pragma unroll
      for (int ct=0;ct<2;ct++)
        aw[ct] = *(const bf16x8*)(W1c + c*32768 + ks*4096 + w*1024 + ct*512 + lane*8);
      #pragma unroll
      for (int ct=0;ct<2;ct++)
        #pragma unroll
        for (int tt=0;tt<4;tt++)
          midv[ct][tt] = __builtin_amdgcn_mfma_f32_16x16x32_bf16(aw[ct], bt[tt], midv[ct][tt], 0,0,0);
    }
    __syncthreads();       // prior FFN2 reads of mid done
    #pragma unroll
    for (int ct=0;ct<2;ct++)
      #pragma unroll
      for (int tt=0;tt<4;tt++){
        uint2 p;
        p.x = pk2(fmaxf(midv[ct][tt][0],0.f), fmaxf(midv[ct][tt][1],0.f));
        p.y = pk2(fmaxf(midv[ct][tt][2],0.f), fmaxf(midv[ct][tt][3],0.f));
        *(uint2*)&mid_sh[tt*16+lr][w*32 + ct*16 + lg*4] = p;
      }
    __syncthreads();
    __builtin_amdgcn_s_setprio(1);
    #pragma unroll
    for (int ks2=0; ks2<4; ks2++){
      bf16x8 aw2[4], bm[4];
      #pragma unroll
      for (int et=0;et<4;et++)
        aw2[et] = *(const bf16x8*)(W2c + c*32768 + ks2*8192 + w*2048 + et*512 + lane*8);
      #pragma unroll
      for (int tt=0;tt<4;tt++) bm[tt] = *(const bf16x8*)&mid_sh[tt*16+lr][ks2*32 + lg*8];
      #pragma unroll
      for (int et=0;et<4;et++)
        #pragma unroll
        for (int tt=0;tt<4;tt++)
          acc[et][tt] = __builtin_amdgcn_mfma_f32_16x16x32_bf16(aw2[et], bm[tt], acc[et][tt], 0,0,0);
    }
    __builtin_amdgcn_s_setprio(0);
  }

  // ---------- t2 = LN(t1 + ffn), delta, z_out, o ----------
  f32x4 b24[4], g24[4], be24[4], wop4[4];
  #pragma unroll
  for (int et=0;et<4;et++){
    int e0_ = cb + et*16 + lg*4;
    b24[et]  = *(const f32x4*)(b2 + e0_);
    g24[et]  = *(const f32x4*)(g2 + e0_);
    be24[et] = *(const f32x4*)(be2 + e0_);
    wop4[et] = *(const f32x4*)(Wop + e0_);
  }
  float sum2[4], ssq2[4];
  #pragma unroll
  for (int tt=0;tt<4;tt++){
    int tok = tt*16 + lr;
    float s = 0.f, sq = 0.f;
    #pragma unroll
    for (int et=0;et<4;et++){
      uint2 t1v = *(const uint2*)&t1_sh[tok][cb + et*16 + lg*4];
      #pragma unroll
      for (int r=0;r<4;r++){
        unsigned short hs = (unsigned short)((r&1) ? ((r<2?t1v.x:t1v.y)>>16) : ((r<2?t1v.x:t1v.y)&0xFFFF));
        float v = acc[et][tt][r] + b24[et][r] + b2f(hs);
        acc[et][tt][r] = v; s += v; sq += v*v;
      }
    }
    s  += __shfl_xor(s,16);  s  += __shfl_xor(s,32);
    sq += __shfl_xor(sq,16); sq += __shfl_xor(sq,32);
    sum2[tt] = s; ssq2[tt] = sq;
  }
  if (lane < 16){
    #pragma unroll
    for (int tt=0;tt<4;tt++){ redA[w][tt*16+lane] = sum2[tt]; redB[w][tt*16+lane] = ssq2[tt]; }
  }
  __syncthreads();   // B2

  float dpart[4];
  #pragma unroll
  for (int tt=0;tt<4;tt++){
    int tok = tt*16 + lr;
    float s  = redA[0][tok] + redA[1][tok] + redA[2][tok] + redA[3][tok];
    float sq = redB[0][tok] + redB[1][tok] + redB[2][tok] + redB[3][tok];
    float m = s * (1.f/256.f);
    float rs = rsqrtf(sq*(1.f/256.f) - m*m + 1e-5f);
    float d = 0.f;
    #pragma unroll
    for (int et=0;et<4;et++)
      #pragma unroll
      for (int r=0;r<4;r++){
        float t2 = (acc[et][tt][r]-m)*rs*g24[et][r] + be24[et][r];
        d += t2*wop4[et][r];
      }
    d += __shfl_xor(d,16); d += __shfl_xor(d,32);
    dpart[tt] = d;
  }
  __syncthreads();   // N1
  if (lane < 16){
    #pragma unroll
    for (int tt=0;tt<4;tt++) redA[w][tt*16+lane] = dpart[tt];
  }
  __syncthreads();   // D2
  if (tid < 64){
    float delta = redA[0][tid]+redA[1][tid]+redA[2][tid]+redA[3][tid] + bop[0];
    float zo = z_sh[tid] + gate_sh[tid]*delta;
    out[49152 + (size_t)n*64 + tid] = zo;
    z_sh[tid] = zo;
  }
  __syncthreads();   // E2
  if (tid < 24){
    const float* ar = Amat + tid*64;
    float s = cvec[tid];
    #pragma unroll
    for (int j=0;j<64;j++) s += z_sh[j]*ar[j];
    out[(size_t)n*24 + tid] = s;
  }
}

extern "C" void kernel_launch(void* const* d_in, const int* in_sizes, int n_in,
                              void* d_out, int out_size, void* d_ws, size_t ws_size,
                              hipStream_t stream) {
  const float* x_cont = (const float*)d_in[0];
  const float* z0    = (const float*)d_in[1];
  const float* W_ih  = (const float*)d_in[2];
  const float* W_hh  = (const float*)d_in[3];
  const float* b_ih  = (const float*)d_in[4];
  const float* b_hh  = (const float*)d_in[5];
  const float* Uf    = (const float*)d_in[6];
  const float* Wfp   = (const float*)d_in[7];
  const float* bfp   = (const float*)d_in[8];
  const float* FE    = (const float*)d_in[9];
  const float* W_in  = (const float*)d_in[10];
  const float* b_in  = (const float*)d_in[11];
  const float* W_ao  = (const float*)d_in[12];
  const float* b_ao  = (const float*)d_in[13];
  const float* g1    = (const float*)d_in[14];
  const float* be1   = (const float*)d_in[15];
  const float* W1    = (const float*)d_in[16];
  const float* b1    = (const float*)d_in[17];
  const float* W2    = (const float*)d_in[18];
  const float* b2    = (const float*)d_in[19];
  const float* g2    = (const float*)d_in[20];
  const float* be2   = (const float*)d_in[21];
  const float* Wop   = (const float*)d_in[22];
  const float* bop   = (const float*)d_in[23];
  const float* Wg    = (const float*)d_in[24];
  const float* bg    = (const float*)d_in[25];
  const float* Amat  = (const float*)d_in[26];
  const float* cvec  = (const float*)d_in[27];
  float* out = (float*)d_out;
  char* ws = (char*)d_ws;

  float* z    = (float*)(ws + 0);         // 524288
  float* Qm   = (float*)(ws + 524288);
  float* Km   = (float*)(ws + 589824);
  float* Vm   = (float*)(ws + 655360);
  float* Gc   = (float*)(ws + 720896);
  float* U    = (float*)(ws + 851968);
  float* Wb   = (float*)(ws + 854016);
  float* S    = (float*)(ws + 856064);
  float* ab   = (float*)(ws + 856320);
  short* M2c  = (short*)(ws + 857344);
  short* W1c  = (short*)(ws + 1119488);
  short* W2c  = (short*)(ws + 1643776);
  float* FEc  = (float*)(ws + 2168064);
  float* preA = (float*)(ws + 2233600);
  float* fzA  = (float*)(ws + 2757888);

  hipLaunchKernelGGL(k_pre1, dim3(704), dim3(256), 0, stream,
                     FE, W_in, Qm, Km, Vm,
                     x_cont, W_ih, b_ih, b_hh, Uf, Wfp, bfp, preA, fzA);
  hipLaunchKernelGGL(k_pre2, dim3(2774), dim3(256), 0, stream,
                     Qm, Km, Vm, b_in, W_ao, b_ao, FE, Gc, U, Wb, S, ab, M2c,
                     W1, W2, W1c, W2c, FEc,
                     z0, W_hh, preA, fzA, z);
  hipLaunchKernelGGL(k_main, dim3(2048), dim3(256), 0, stream, z, Gc, U, Wb, S, ab, M2c, FEc,
                     W1c, b1, W2c, b2, g1, be1, g2, be2, Wop, bop, Wg, bg, Amat, cvec, out);
}